// Round 1
// baseline (339.687 us; speedup 1.0000x reference)
//
#include <hip/hip_runtime.h>
#include <cstddef>

#define Bq 64
#define Tq 90
#define Oq 5
#define Dq 256
#define Hq 256
#define EAq 4096
#define Rq 5
#define NBq 8
#define NPGq 95
#define Nq 6080           // B*NPG
#define EPBq 4546         // EA + T*O
#define Eq 290944         // B*EPB
#define ARq 475           // NPG*R rows of A per graph
#define KCq 1792          // (R+1)*D

// ---------------- Wcat[kk][h]: rows 0..1535 = W[r][d][:], rows 1536.. = root[d][:]
__global__ void k_wcat(const float* __restrict__ bases, const float* __restrict__ comp,
                       const float* __restrict__ rootw, float* __restrict__ Wcat) {
    int kk = blockIdx.x;          // 0..KCq-1
    int h  = threadIdx.x;         // 0..255
    float v;
    if (kk < Rq * Dq) {
        int r = kk >> 8, d = kk & 255;
        float s = 0.f;
#pragma unroll
        for (int nb = 0; nb < NBq; ++nb)
            s += comp[r * NBq + nb] * bases[((size_t)nb * Dq + d) * Hq + h];
        v = s;
    } else {
        v = rootw[(size_t)(kk - Rq * Dq) * Hq + h];
    }
    Wcat[(size_t)kk * Hq + h] = v;
}

// ---------------- scale[b][t][s] = M[b,t,:] . Ws[s,:]
__global__ __launch_bounds__(128) void k_scale(const float* __restrict__ M,
                                               const float* __restrict__ Ws,
                                               float* __restrict__ scale) {
    __shared__ float Ms[Dq];
    int bt = blockIdx.x;          // b*T + t
    int tid = threadIdx.x;
    Ms[tid]       = M[(size_t)bt * Dq + tid];
    Ms[tid + 128] = M[(size_t)bt * Dq + tid + 128];
    __syncthreads();
    if (tid < Tq) {
        const float4* w4 = (const float4*)(Ws + (size_t)tid * Dq);
        const float4* m4 = (const float4*)Ms;
        float acc = 0.f;
#pragma unroll 4
        for (int i = 0; i < Dq / 4; ++i) {
            float4 a = m4[i], w = w4[i];
            acc += a.x * w.x + a.y * w.y + a.z * w.z + a.w * w.w;
        }
        scale[(size_t)bt * Tq + tid] = acc;
    }
}

// ---------------- per-(b,s) column softmax stats over t
__global__ void k_stats(const float* __restrict__ scale, float* __restrict__ mxv,
                        float* __restrict__ den) {
    int g = blockIdx.x * blockDim.x + threadIdx.x;
    if (g >= Bq * Tq) return;
    int b = g / Tq, s = g % Tq;
    const float* col = scale + (size_t)b * Tq * Tq + s;
    float m = -1e30f;
    for (int t = 0; t < Tq; ++t) m = fmaxf(m, col[(size_t)t * Tq]);
    float sum = 0.f;
    for (int t = 0; t < Tq; ++t) sum += expf(col[(size_t)t * Tq] - m);
    mxv[g] = m;
    den[g] = sum;
}

// ---------------- scatter scalar norms into A[b][dst*R+r][src]
__global__ void k_edges(const float* __restrict__ scale, const float* __restrict__ mxv,
                        const float* __restrict__ den, const float* __restrict__ natt,
                        const int* __restrict__ esrc, const int* __restrict__ edst,
                        const int* __restrict__ etype, float* __restrict__ Am) {
    int e = blockIdx.x * blockDim.x + threadIdx.x;
    if (e >= Eq) return;
    int b = e / EPBq, j = e % EPBq;
    float norm;
    int row, col;
    if (j < EAq) {
        int s  = esrc[(size_t)b * EAq + j];
        int dt = edst[(size_t)b * EAq + j];
        int r  = etype[(size_t)b * EAq + j];
        norm = expf(scale[((size_t)b * Tq + dt) * Tq + s] - mxv[b * Tq + s]) / den[b * Tq + s];
        row = dt * Rq + r;
        col = s;
    } else {
        int i = j - EAq;
        int t = i / Oq, o = i % Oq;
        norm = natt[(size_t)b * (Tq * Oq) + i];
        row = (Tq + o) * Rq + (Rq - 1);
        col = t;
    }
    atomicAdd(&Am[((size_t)b * ARq + row) * Tq + col], norm);
}

// ---------------- accat[b*95+nl][r*256+d] = sum_s A[b][nl*R+r][s] * x[b*95+s][d]
__global__ __launch_bounds__(256) void k_spmm(const float* __restrict__ Am,
                                              const float* __restrict__ x,
                                              float* __restrict__ accat) {
    __shared__ float Xs[45 * Dq];       // 46 KB
    int slab = blockIdx.x;              // 0..7
    int b    = blockIdx.y;
    int tid  = threadIdx.x;
    int g    = tid >> 6;                // 0..3 (wave id)
    int lane = tid & 63;
    int row0 = slab * 60;
    int rlim = row0 + 60 < ARq ? row0 + 60 : ARq;
    const float* Ab = Am + (size_t)b * ARq * Tq;
    for (int step = 0; step < 4; ++step) {
        int rbase = row0 + step * 16 + g * 4;
        float acc[4][4];
#pragma unroll
        for (int rr = 0; rr < 4; ++rr)
#pragma unroll
            for (int jj = 0; jj < 4; ++jj) acc[rr][jj] = 0.f;
        for (int p = 0; p < 2; ++p) {
            __syncthreads();
            const float4* src = (const float4*)(x + (size_t)(b * NPGq + p * 45) * Dq);
            float4* dst4 = (float4*)Xs;
            for (int i = tid; i < 45 * 64; i += 256) dst4[i] = src[i];
            __syncthreads();
            for (int k = 0; k < 45; ++k) {
                float4 xv = ((const float4*)Xs)[k * 64 + lane];
#pragma unroll
                for (int rr = 0; rr < 4; ++rr) {
                    int r = rbase + rr;
                    float a = (r < rlim) ? Ab[(size_t)r * Tq + p * 45 + k] : 0.f;
                    acc[rr][0] += a * xv.x;
                    acc[rr][1] += a * xv.y;
                    acc[rr][2] += a * xv.z;
                    acc[rr][3] += a * xv.w;
                }
            }
        }
#pragma unroll
        for (int rr = 0; rr < 4; ++rr) {
            int r = rbase + rr;
            if (r < rlim) {
                int nl = r / Rq, rc = r % Rq;
                float4 v = make_float4(acc[rr][0], acc[rr][1], acc[rr][2], acc[rr][3]);
                *(float4*)(accat + (size_t)(b * NPGq + nl) * KCq + rc * Dq + lane * 4) = v;
            }
        }
    }
}

// ---------------- copy x into last D columns of accat
__global__ void k_xcopy(const float* __restrict__ x, float* __restrict__ accat) {
    int i = blockIdx.x * blockDim.x + threadIdx.x;   // over N*64 float4s
    if (i >= Nq * 64) return;
    int n = i >> 6, c = i & 63;
    ((float4*)(accat + (size_t)n * KCq + Rq * Dq))[c] = ((const float4*)(x + (size_t)n * Dq))[c];
}

// ---------------- out init with bias
__global__ void k_outinit(const float* __restrict__ bias, float* __restrict__ out) {
    int i = blockIdx.x * 256 + threadIdx.x;
    out[(size_t)i] = bias[i & (Hq - 1)];
}

// ---------------- out += accat @ Wcat   (split-K=4, fp32 atomics)
__global__ __launch_bounds__(256) void k_gemm(const float* __restrict__ Acc,
                                              const float* __restrict__ Wc,
                                              float* __restrict__ out) {
    __shared__ float As[16][64];
    __shared__ float Bs[16][64];
    int bm = blockIdx.x, bn = blockIdx.y, bz = blockIdx.z;
    int tid = threadIdx.x;
    int tx = tid & 15, ty = tid >> 4;
    int m0 = bm * 64, n0 = bn * 64;
    float acc[4][4] = {};
    int kbeg = bz * (KCq / 4), kend = kbeg + (KCq / 4);
    int lr = tid >> 2, lk = (tid & 3) * 4;   // A-tile load coords (64 rows x 16 k)
    int wr = tid >> 4, wc = (tid & 15) * 4;  // B-tile load coords (16 k x 64 cols)
    for (int k0 = kbeg; k0 < kend; k0 += 16) {
        float4 av = *(const float4*)(Acc + (size_t)(m0 + lr) * KCq + k0 + lk);
        float4 wv = *(const float4*)(Wc + (size_t)(k0 + wr) * Hq + n0 + wc);
        As[lk + 0][lr] = av.x;
        As[lk + 1][lr] = av.y;
        As[lk + 2][lr] = av.z;
        As[lk + 3][lr] = av.w;
        *(float4*)&Bs[wr][wc] = wv;
        __syncthreads();
#pragma unroll
        for (int k = 0; k < 16; ++k) {
            float4 a = *(const float4*)&As[k][ty * 4];
            float4 b = *(const float4*)&Bs[k][tx * 4];
            acc[0][0] += a.x * b.x; acc[0][1] += a.x * b.y; acc[0][2] += a.x * b.z; acc[0][3] += a.x * b.w;
            acc[1][0] += a.y * b.x; acc[1][1] += a.y * b.y; acc[1][2] += a.y * b.z; acc[1][3] += a.y * b.w;
            acc[2][0] += a.z * b.x; acc[2][1] += a.z * b.y; acc[2][2] += a.z * b.z; acc[2][3] += a.z * b.w;
            acc[3][0] += a.w * b.x; acc[3][1] += a.w * b.y; acc[3][2] += a.w * b.z; acc[3][3] += a.w * b.w;
        }
        __syncthreads();
    }
#pragma unroll
    for (int i = 0; i < 4; ++i) {
        float* orow = out + (size_t)(m0 + ty * 4 + i) * Hq + n0 + tx * 4;
        atomicAdd(orow + 0, acc[i][0]);
        atomicAdd(orow + 1, acc[i][1]);
        atomicAdd(orow + 2, acc[i][2]);
        atomicAdd(orow + 3, acc[i][3]);
    }
}

extern "C" void kernel_launch(void* const* d_in, const int* in_sizes, int n_in,
                              void* d_out, int out_size, void* d_ws, size_t ws_size,
                              hipStream_t stream) {
    (void)in_sizes; (void)n_in; (void)out_size; (void)ws_size;
    const float* M     = (const float*)d_in[0];
    const float* x     = (const float*)d_in[1];
    const float* natt  = (const float*)d_in[2];
    const float* Ws    = (const float*)d_in[3];
    const float* bases = (const float*)d_in[4];
    const float* comp  = (const float*)d_in[5];
    const float* rootw = (const float*)d_in[6];
    const float* bias  = (const float*)d_in[7];
    const int* esrc    = (const int*)d_in[8];
    const int* edst    = (const int*)d_in[9];
    const int* etype   = (const int*)d_in[10];
    float* out = (float*)d_out;
    char* ws = (char*)d_ws;

    float* Wcat  = (float*)(ws + 0);          // 1,835,008 B
    float* scale = (float*)(ws + 1835008);    // 2,073,600 B
    float* mxv   = (float*)(ws + 3908608);    //    23,040 B
    float* den   = (float*)(ws + 3931648);    //    23,040 B
    float* Am    = (float*)(ws + 3954688);    // 10,944,000 B
    float* accat = (float*)(ws + 14898688);   // 43,581,440 B  (total 58.5 MB)

    hipMemsetAsync(Am, 0, 10944000, stream);
    k_wcat<<<dim3(KCq), 256, 0, stream>>>(bases, comp, rootw, Wcat);
    k_scale<<<dim3(Bq * Tq), 128, 0, stream>>>(M, Ws, scale);
    k_stats<<<dim3((Bq * Tq + 255) / 256), 256, 0, stream>>>(scale, mxv, den);
    k_edges<<<dim3((Eq + 255) / 256), 256, 0, stream>>>(scale, mxv, den, natt,
                                                        esrc, edst, etype, Am);
    k_spmm<<<dim3(8, Bq), 256, 0, stream>>>(Am, x, accat);
    k_xcopy<<<dim3((Nq * 64 + 255) / 256), 256, 0, stream>>>(x, accat);
    k_outinit<<<dim3(Nq * Hq / 256), 256, 0, stream>>>(bias, out);
    k_gemm<<<dim3(95, 4, 4), 256, 0, stream>>>(accat, Wcat, out);
}

// Round 2
// 230.104 us; speedup vs baseline: 1.4762x; 1.4762x over previous
//
#include <hip/hip_runtime.h>
#include <cstddef>
#include <cstdint>

#define Bq 64
#define Tq 90
#define Oq 5
#define Dq 256
#define Hq 256
#define EAq 4096
#define Rq 5
#define NBq 8
#define NPGq 95
#define Nq 6080           // B*NPG
#define EPBq 4546         // EA + T*O
#define Eq 290944         // B*EPB
#define ARq 475           // NPG*R rows of A per graph
#define KCq 1536          // (R+1)*D

typedef __attribute__((ext_vector_type(8))) short bf16x8;
typedef __attribute__((ext_vector_type(4))) float f32x4;
typedef __attribute__((address_space(1))) const unsigned int gu32;
typedef __attribute__((address_space(3))) unsigned int lu32;

__device__ __forceinline__ unsigned short f2bf(float f) {
    unsigned u = __float_as_uint(f);
    unsigned r = (u + 0x7FFF + ((u >> 16) & 1)) >> 16;
    return (unsigned short)r;
}

// ---------------- WcatT[h][kk] (bf16): kk<1280 -> W[r=kk>>8][d=kk&255][h], else root[kk-1280][h]
__global__ void k_wcat(const float* __restrict__ bases, const float* __restrict__ comp,
                       const float* __restrict__ rootw, unsigned short* __restrict__ WcatT) {
    int kk = blockIdx.x;          // 0..KCq-1
    int h  = threadIdx.x;         // 0..255
    float v;
    if (kk < Rq * Dq) {
        int r = kk >> 8, d = kk & 255;
        float s = 0.f;
#pragma unroll
        for (int nb = 0; nb < NBq; ++nb)
            s += comp[r * NBq + nb] * bases[((size_t)nb * Dq + d) * Hq + h];
        v = s;
    } else {
        v = rootw[(size_t)(kk - Rq * Dq) * Hq + h];
    }
    WcatT[(size_t)h * KCq + kk] = f2bf(v);
}

// ---------------- scale[b][t][s] = M[b,t,:] . Ws[s,:]
__global__ __launch_bounds__(128) void k_scale(const float* __restrict__ M,
                                               const float* __restrict__ Ws,
                                               float* __restrict__ scale) {
    __shared__ float Ms[Dq];
    int bt = blockIdx.x;          // b*T + t
    int tid = threadIdx.x;
    Ms[tid]       = M[(size_t)bt * Dq + tid];
    Ms[tid + 128] = M[(size_t)bt * Dq + tid + 128];
    __syncthreads();
    if (tid < Tq) {
        const float4* w4 = (const float4*)(Ws + (size_t)tid * Dq);
        const float4* m4 = (const float4*)Ms;
        float acc = 0.f;
#pragma unroll 4
        for (int i = 0; i < Dq / 4; ++i) {
            float4 a = m4[i], w = w4[i];
            acc += a.x * w.x + a.y * w.y + a.z * w.z + a.w * w.w;
        }
        scale[(size_t)bt * Tq + tid] = acc;
    }
}

// ---------------- per-(b,s) column softmax stats over t
__global__ void k_stats(const float* __restrict__ scale, float* __restrict__ mxv,
                        float* __restrict__ den) {
    int g = blockIdx.x * blockDim.x + threadIdx.x;
    if (g >= Bq * Tq) return;
    int b = g / Tq, s = g % Tq;
    const float* col = scale + (size_t)b * Tq * Tq + s;
    float m = -1e30f;
    for (int t = 0; t < Tq; ++t) m = fmaxf(m, col[(size_t)t * Tq]);
    float sum = 0.f;
    for (int t = 0; t < Tq; ++t) sum += expf(col[(size_t)t * Tq] - m);
    mxv[g] = m;
    den[g] = sum;
}

// ---------------- scatter scalar norms into A[b][dst*R+r][src]
__global__ void k_edges(const float* __restrict__ scale, const float* __restrict__ mxv,
                        const float* __restrict__ den, const float* __restrict__ natt,
                        const int* __restrict__ esrc, const int* __restrict__ edst,
                        const int* __restrict__ etype, float* __restrict__ Am) {
    int e = blockIdx.x * blockDim.x + threadIdx.x;
    if (e >= Eq) return;
    int b = e / EPBq, j = e % EPBq;
    float norm;
    int row, col;
    if (j < EAq) {
        int s  = esrc[(size_t)b * EAq + j];
        int dt = edst[(size_t)b * EAq + j];
        int r  = etype[(size_t)b * EAq + j];
        norm = expf(scale[((size_t)b * Tq + dt) * Tq + s] - mxv[b * Tq + s]) / den[b * Tq + s];
        row = dt * Rq + r;
        col = s;
    } else {
        int i = j - EAq;
        int t = i / Oq, o = i % Oq;
        norm = natt[(size_t)b * (Tq * Oq) + i];
        row = (Tq + o) * Rq + (Rq - 1);
        col = t;
    }
    atomicAdd(&Am[((size_t)b * ARq + row) * Tq + col], norm);
}

// ---------------- accat[b*95+nl][rc*256+d] = sum_s A[b][nl*R+rc][s] * x[b*95+s][d]  (bf16 out)
__global__ __launch_bounds__(256) void k_spmm(const float* __restrict__ Am,
                                              const float* __restrict__ x,
                                              unsigned short* __restrict__ accat) {
    __shared__ float Xs[45 * Dq];       // 46 KB
    int slab = blockIdx.x;              // 0..7
    int b    = blockIdx.y;
    int tid  = threadIdx.x;
    int g    = tid >> 6;                // wave id
    int lane = tid & 63;
    int row0 = slab * 60;
    int rlim = row0 + 60 < ARq ? row0 + 60 : ARq;
    const float* Ab = Am + (size_t)b * ARq * Tq;
    for (int step = 0; step < 4; ++step) {
        int rbase = row0 + step * 16 + g * 4;
        float acc[4][4];
#pragma unroll
        for (int rr = 0; rr < 4; ++rr)
#pragma unroll
            for (int jj = 0; jj < 4; ++jj) acc[rr][jj] = 0.f;
        for (int p = 0; p < 2; ++p) {
            __syncthreads();
            const float4* src = (const float4*)(x + (size_t)(b * NPGq + p * 45) * Dq);
            float4* dst4 = (float4*)Xs;
            for (int i = tid; i < 45 * 64; i += 256) dst4[i] = src[i];
            __syncthreads();
            for (int k = 0; k < 45; ++k) {
                float4 xv = ((const float4*)Xs)[k * 64 + lane];
#pragma unroll
                for (int rr = 0; rr < 4; ++rr) {
                    int r = rbase + rr;
                    float a = (r < rlim) ? Ab[(size_t)r * Tq + p * 45 + k] : 0.f;
                    acc[rr][0] += a * xv.x;
                    acc[rr][1] += a * xv.y;
                    acc[rr][2] += a * xv.z;
                    acc[rr][3] += a * xv.w;
                }
            }
        }
#pragma unroll
        for (int rr = 0; rr < 4; ++rr) {
            int r = rbase + rr;
            if (r < rlim) {
                int nl = r / Rq, rc = r % Rq;
                ushort4 pk;
                pk.x = f2bf(acc[rr][0]); pk.y = f2bf(acc[rr][1]);
                pk.z = f2bf(acc[rr][2]); pk.w = f2bf(acc[rr][3]);
                *(ushort4*)(accat + (size_t)(b * NPGq + nl) * KCq + rc * Dq + lane * 4) = pk;
            }
        }
    }
}

// ---------------- copy x (bf16) into last D columns of accat
__global__ void k_xbf(const float* __restrict__ x, unsigned short* __restrict__ accat) {
    int i = blockIdx.x * blockDim.x + threadIdx.x;   // over Nq*32 chunks of 8
    if (i >= Nq * 32) return;
    int n = i >> 5, c = i & 31;
    const float4* xs = (const float4*)(x + (size_t)n * Dq + c * 8);
    float4 a = xs[0], bvec = xs[1];
    ushort4 p0, p1;
    p0.x = f2bf(a.x); p0.y = f2bf(a.y); p0.z = f2bf(a.z); p0.w = f2bf(a.w);
    p1.x = f2bf(bvec.x); p1.y = f2bf(bvec.y); p1.z = f2bf(bvec.z); p1.w = f2bf(bvec.w);
    ushort4* dst = (ushort4*)(accat + (size_t)n * KCq + Rq * Dq + c * 8);
    dst[0] = p0; dst[1] = p1;
}

// ---------------- out = accat @ WcatT^T + bias   (bf16 MFMA, 64x64 tiles, BK=64, dbuf glds)
__global__ __launch_bounds__(256) void k_gemm(const unsigned short* __restrict__ A,
                                              const unsigned short* __restrict__ Bt,
                                              const float* __restrict__ bias,
                                              float* __restrict__ out) {
    __shared__ float4 lds4[2][1024];    // per buf: As 8KB @0, Bs 8KB @8192
    const int tid = threadIdx.x;
    const int m0 = blockIdx.x * 64, n0 = blockIdx.y * 64;
    const int w = tid >> 6, l = tid & 63;
    const int wr = w >> 1, wc = w & 1;
    const int srow = tid >> 3;          // 0..31
    const int sc = tid & 7;

    f32x4 acc[2][2];
#pragma unroll
    for (int i = 0; i < 2; ++i)
#pragma unroll
        for (int j = 0; j < 2; ++j) acc[i][j] = (f32x4)0.0f;

    char* const lbase0 = (char*)&lds4[0][0];
    char* const lbase1 = (char*)&lds4[1][0];

    auto stage = [&](char* base, int k0) {
#pragma unroll
        for (int i = 0; i < 2; ++i) {
            int row = i * 32 + srow;
            int csrc = sc ^ (row & 7);
            const unsigned short* g = A + (size_t)(m0 + row) * KCq + k0 + csrc * 8;
            char* ld = base + i * 4096 + w * 1024;
            __builtin_amdgcn_global_load_lds((gu32*)g, (lu32*)(unsigned int)(uintptr_t)ld, 16, 0, 0);
        }
#pragma unroll
        for (int i = 0; i < 2; ++i) {
            int row = i * 32 + srow;
            int csrc = sc ^ (row & 7);
            const unsigned short* g = Bt + (size_t)(n0 + row) * KCq + k0 + csrc * 8;
            char* ld = base + 8192 + i * 4096 + w * 1024;
            __builtin_amdgcn_global_load_lds((gu32*)g, (lu32*)(unsigned int)(uintptr_t)ld, 16, 0, 0);
        }
    };

    stage(lbase0, 0);
    __syncthreads();

    int cur = 0;
    for (int t = 0; t < KCq / 64; ++t) {
        char* base = cur ? lbase1 : lbase0;
        if (t < KCq / 64 - 1) stage(cur ? lbase0 : lbase1, (t + 1) * 64);

        bf16x8 af[2][2], bfr[2][2];
#pragma unroll
        for (int ks = 0; ks < 2; ++ks) {
            int koff = ks * 64 + (l >> 4) * 16;
#pragma unroll
            for (int mi = 0; mi < 2; ++mi) {
                int row = wr * 32 + mi * 16 + (l & 15);
                af[mi][ks] = *(const bf16x8*)(base + row * 128 + (koff ^ ((row & 7) << 4)));
            }
#pragma unroll
            for (int ni = 0; ni < 2; ++ni) {
                int row = wc * 32 + ni * 16 + (l & 15);
                bfr[ni][ks] = *(const bf16x8*)(base + 8192 + row * 128 + (koff ^ ((row & 7) << 4)));
            }
        }
#pragma unroll
        for (int ks = 0; ks < 2; ++ks)
#pragma unroll
            for (int mi = 0; mi < 2; ++mi)
#pragma unroll
                for (int ni = 0; ni < 2; ++ni)
                    acc[mi][ni] = __builtin_amdgcn_mfma_f32_16x16x32_bf16(
                        af[mi][ks], bfr[ni][ks], acc[mi][ni], 0, 0, 0);
        __syncthreads();
        cur ^= 1;
    }

#pragma unroll
    for (int mi = 0; mi < 2; ++mi)
#pragma unroll
        for (int ni = 0; ni < 2; ++ni) {
            int n = n0 + wc * 32 + ni * 16 + (l & 15);
            float bv = bias[n];
#pragma unroll
            for (int j = 0; j < 4; ++j) {
                int m = m0 + wr * 32 + mi * 16 + (l >> 4) * 4 + j;
                out[(size_t)m * Hq + n] = acc[mi][ni][j] + bv;
            }
        }
}

extern "C" void kernel_launch(void* const* d_in, const int* in_sizes, int n_in,
                              void* d_out, int out_size, void* d_ws, size_t ws_size,
                              hipStream_t stream) {
    (void)in_sizes; (void)n_in; (void)out_size; (void)ws_size;
    const float* M     = (const float*)d_in[0];
    const float* x     = (const float*)d_in[1];
    const float* natt  = (const float*)d_in[2];
    const float* Ws    = (const float*)d_in[3];
    const float* bases = (const float*)d_in[4];
    const float* comp  = (const float*)d_in[5];
    const float* rootw = (const float*)d_in[6];
    const float* bias  = (const float*)d_in[7];
    const int* esrc    = (const int*)d_in[8];
    const int* edst    = (const int*)d_in[9];
    const int* etype   = (const int*)d_in[10];
    float* out = (float*)d_out;
    char* ws = (char*)d_ws;

    unsigned short* WcatT = (unsigned short*)(ws + 0);   //   786,432 B
    float* scale = (float*)(ws + 786432);                // 2,073,600 B
    float* mxv   = (float*)(ws + 2860032);               //    23,040 B
    float* den   = (float*)(ws + 2883072);               //    23,040 B
    float* Am    = (float*)(ws + 2906112);               // 10,944,000 B
    unsigned short* accat = (unsigned short*)(ws + 13850112); // 18,677,760 B (total ~32.5 MB)

    hipMemsetAsync(Am, 0, 10944000, stream);
    k_wcat<<<dim3(KCq), 256, 0, stream>>>(bases, comp, rootw, WcatT);
    k_scale<<<dim3(Bq * Tq), 128, 0, stream>>>(M, Ws, scale);
    k_stats<<<dim3((Bq * Tq + 255) / 256), 256, 0, stream>>>(scale, mxv, den);
    k_edges<<<dim3((Eq + 255) / 256), 256, 0, stream>>>(scale, mxv, den, natt,
                                                        esrc, edst, etype, Am);
    k_spmm<<<dim3(8, Bq), 256, 0, stream>>>(Am, x, accat);
    k_xbf<<<dim3((Nq * 32 + 255) / 256), 256, 0, stream>>>(x, accat);
    k_gemm<<<dim3(Nq / 64, Hq / 64), 256, 0, stream>>>(accat, WcatT, bias, out);
}

// Round 3
// 160.724 us; speedup vs baseline: 2.1135x; 1.4317x over previous
//
#include <hip/hip_runtime.h>
#include <cstddef>
#include <cstdint>

#define Bq 64
#define Tq 90
#define Oq 5
#define Dq 256
#define Hq 256
#define EAq 4096
#define Rq 5
#define NBq 8
#define NPGq 95
#define Nq 6080           // B*NPG real nodes
#define NPq 6144          // padded node space: 64 graphs x 96
#define EPBq 4546         // EA + T*O
#define Eq 290944         // B*EPB
#define KKq 1536          // (R+1)*D rows of WT / xwT
#define KAq 480           // A2 cols: 5 relations x 96

typedef __attribute__((ext_vector_type(8))) short bf16x8;
typedef __attribute__((ext_vector_type(8))) unsigned short u16x8;
typedef __attribute__((ext_vector_type(4))) float f32x4;
typedef __attribute__((address_space(1))) const unsigned int gu32;
typedef __attribute__((address_space(3))) unsigned int lu32;

__device__ __forceinline__ unsigned short f2bf(float f) {
    unsigned u = __float_as_uint(f);
    unsigned r = (u + 0x7FFF + ((u >> 16) & 1)) >> 16;
    return (unsigned short)r;
}
__device__ __forceinline__ float bf2f(unsigned short s) {
    return __uint_as_float(((unsigned)s) << 16);
}

// ---------------- WT[kk][d] bf16: kk=r*256+h -> sum_nb comp[r][nb]*bases[nb][d][h]; kk=1280+h -> root[d][h]
__global__ __launch_bounds__(256) void k_wt(const float* __restrict__ bases,
                                            const float* __restrict__ comp,
                                            const float* __restrict__ rootw,
                                            unsigned short* __restrict__ Wt) {
    __shared__ float Ld[32][257];
    int rs = blockIdx.x;          // 0..5 (5 = root slice)
    int d0 = blockIdx.y * 32;
    int t = threadIdx.x;          // h
    float cmp[NBq];
    if (rs < Rq)
#pragma unroll
        for (int nb = 0; nb < NBq; ++nb) cmp[nb] = comp[rs * NBq + nb];
    for (int dl = 0; dl < 32; ++dl) {
        int d = d0 + dl;
        float v;
        if (rs < Rq) {
            v = 0.f;
#pragma unroll
            for (int nb = 0; nb < NBq; ++nb)
                v += cmp[nb] * bases[((size_t)nb * Dq + d) * Hq + t];
        } else {
            v = rootw[(size_t)d * Hq + t];
        }
        Ld[dl][t] = v;
    }
    __syncthreads();
    int c = t & 31, hg = t >> 5;
    for (int hh = 0; hh < 32; ++hh) {
        int h = hg * 32 + hh;
        Wt[(size_t)(rs * 256 + h) * Dq + d0 + c] = f2bf(Ld[c][h]);
    }
}

// ---------------- scale[b][t][s] = M[b,t,:] . Ws[s,:]
__global__ __launch_bounds__(128) void k_scale(const float* __restrict__ M,
                                               const float* __restrict__ Ws,
                                               float* __restrict__ scale) {
    __shared__ float Ms[Dq];
    int bt = blockIdx.x;
    int tid = threadIdx.x;
    Ms[tid]       = M[(size_t)bt * Dq + tid];
    Ms[tid + 128] = M[(size_t)bt * Dq + tid + 128];
    __syncthreads();
    if (tid < Tq) {
        const float4* w4 = (const float4*)(Ws + (size_t)tid * Dq);
        const float4* m4 = (const float4*)Ms;
        float acc = 0.f;
#pragma unroll 4
        for (int i = 0; i < Dq / 4; ++i) {
            float4 a = m4[i], w = w4[i];
            acc += a.x * w.x + a.y * w.y + a.z * w.z + a.w * w.w;
        }
        scale[(size_t)bt * Tq + tid] = acc;
    }
}

// ---------------- per-(b,s) column softmax stats over t
__global__ void k_stats(const float* __restrict__ scale, float* __restrict__ mxv,
                        float* __restrict__ den) {
    int g = blockIdx.x * blockDim.x + threadIdx.x;
    if (g >= Bq * Tq) return;
    int b = g / Tq, s = g % Tq;
    const float* col = scale + (size_t)b * Tq * Tq + s;
    float m = -1e30f;
    for (int t = 0; t < Tq; ++t) m = fmaxf(m, col[(size_t)t * Tq]);
    float sum = 0.f;
    for (int t = 0; t < Tq; ++t) sum += expf(col[(size_t)t * Tq] - m);
    mxv[g] = m;
    den[g] = sum;
}

// ---------------- scatter scalar norms into A2f[b][dst][r*96+src]
__global__ void k_edges(const float* __restrict__ scale, const float* __restrict__ mxv,
                        const float* __restrict__ den, const float* __restrict__ natt,
                        const int* __restrict__ esrc, const int* __restrict__ edst,
                        const int* __restrict__ etype, float* __restrict__ A2f) {
    int e = blockIdx.x * blockDim.x + threadIdx.x;
    if (e >= Eq) return;
    int b = e / EPBq, j = e % EPBq;
    float norm;
    int row, col;
    if (j < EAq) {
        int s  = esrc[(size_t)b * EAq + j];
        int dt = edst[(size_t)b * EAq + j];
        int r  = etype[(size_t)b * EAq + j];
        norm = expf(scale[((size_t)b * Tq + dt) * Tq + s] - mxv[b * Tq + s]) / den[b * Tq + s];
        row = dt;
        col = r * 96 + s;
    } else {
        int i = j - EAq;
        int t = i / Oq, o = i % Oq;
        norm = natt[(size_t)b * (Tq * Oq) + i];
        row = Tq + o;
        col = (Rq - 1) * 96 + t;
    }
    atomicAdd(&A2f[((size_t)b * 96 + row) * KAq + col], norm);
}

// ---------------- A2f fp32 -> A2b bf16
__global__ void k_a2bf(const float* __restrict__ A2f, unsigned short* __restrict__ A2b) {
    unsigned i = blockIdx.x * blockDim.x + threadIdx.x;   // over 64*96*480/8
    if (i >= (Bq * 96 * KAq) / 8) return;
    const float4* s4 = (const float4*)(A2f + (size_t)i * 8);
    float4 a = s4[0], c = s4[1];
    u16x8 pk;
    pk[0] = f2bf(a.x); pk[1] = f2bf(a.y); pk[2] = f2bf(a.z); pk[3] = f2bf(a.w);
    pk[4] = f2bf(c.x); pk[5] = f2bf(c.y); pk[6] = f2bf(c.z); pk[7] = f2bf(c.w);
    *(u16x8*)(A2b + (size_t)i * 8) = pk;
}

// ---------------- x fp32 [6080][256] -> xb bf16 [6144][256] (row n'=b*96+s, s=95 zero pad)
__global__ void k_xbf(const float* __restrict__ x, unsigned short* __restrict__ xb) {
    unsigned i = blockIdx.x * blockDim.x + threadIdx.x;   // over NPq*32 chunks of 8
    if (i >= NPq * 32) return;
    unsigned np = i >> 5, c = i & 31;
    unsigned s = np % 96;
    u16x8 pk;
    if (s == 95) {
#pragma unroll
        for (int q = 0; q < 8; ++q) pk[q] = 0;
    } else {
        unsigned node = np - np / 96;
        const float4* xs = (const float4*)(x + (size_t)node * Dq + c * 8);
        float4 a = xs[0], b2 = xs[1];
        pk[0] = f2bf(a.x);  pk[1] = f2bf(a.y);  pk[2] = f2bf(a.z);  pk[3] = f2bf(a.w);
        pk[4] = f2bf(b2.x); pk[5] = f2bf(b2.y); pk[6] = f2bf(b2.z); pk[7] = f2bf(b2.w);
    }
    *(u16x8*)(xb + (size_t)np * Dq + c * 8) = pk;
}

// ---------------- xwT[kk][n'] = sum_d WT[kk][d] * xb[n'][d]   (bf16 MFMA, 64x64, K=256, dbuf)
__global__ __launch_bounds__(256) void k_gemm1(const unsigned short* __restrict__ Wt,
                                               const unsigned short* __restrict__ xb,
                                               unsigned short* __restrict__ xwT) {
    __shared__ float4 lds4[2][1024];    // per buf: As 8KB @0, Bs 8KB @8192
    const int tid = threadIdx.x;
    const int m0 = blockIdx.x * 64, n0 = blockIdx.y * 64;
    const int w = tid >> 6, l = tid & 63;
    const int wr = w >> 1, wc = w & 1;
    const int srow = tid >> 3;
    const int sc = tid & 7;

    f32x4 acc[2][2];
#pragma unroll
    for (int i = 0; i < 2; ++i)
#pragma unroll
        for (int j = 0; j < 2; ++j) acc[i][j] = (f32x4)0.0f;

    char* const lbase0 = (char*)&lds4[0][0];
    char* const lbase1 = (char*)&lds4[1][0];

    auto stage = [&](char* base, int k0) {
#pragma unroll
        for (int i = 0; i < 2; ++i) {
            int row = i * 32 + srow;
            int csrc = sc ^ (row & 7);
            const unsigned short* g = Wt + (size_t)(m0 + row) * Dq + k0 + csrc * 8;
            char* ld = base + i * 4096 + w * 1024;
            __builtin_amdgcn_global_load_lds((gu32*)g, (lu32*)(unsigned int)(uintptr_t)ld, 16, 0, 0);
        }
#pragma unroll
        for (int i = 0; i < 2; ++i) {
            int row = i * 32 + srow;
            int csrc = sc ^ (row & 7);
            const unsigned short* g = xb + (size_t)(n0 + row) * Dq + k0 + csrc * 8;
            char* ld = base + 8192 + i * 4096 + w * 1024;
            __builtin_amdgcn_global_load_lds((gu32*)g, (lu32*)(unsigned int)(uintptr_t)ld, 16, 0, 0);
        }
    };

    stage(lbase0, 0);
    __syncthreads();

    int cur = 0;
    for (int t = 0; t < Dq / 64; ++t) {
        char* base = cur ? lbase1 : lbase0;
        if (t < Dq / 64 - 1) stage(cur ? lbase0 : lbase1, (t + 1) * 64);

        bf16x8 af[2][2], bfr[2][2];
#pragma unroll
        for (int ks = 0; ks < 2; ++ks) {
            int koff = ks * 64 + (l >> 4) * 16;
#pragma unroll
            for (int mi = 0; mi < 2; ++mi) {
                int row = wr * 32 + mi * 16 + (l & 15);
                af[mi][ks] = *(const bf16x8*)(base + row * 128 + (koff ^ ((row & 7) << 4)));
            }
#pragma unroll
            for (int ni = 0; ni < 2; ++ni) {
                int row = wc * 32 + ni * 16 + (l & 15);
                bfr[ni][ks] = *(const bf16x8*)(base + 8192 + row * 128 + (koff ^ ((row & 7) << 4)));
            }
        }
#pragma unroll
        for (int ks = 0; ks < 2; ++ks)
#pragma unroll
            for (int mi = 0; mi < 2; ++mi)
#pragma unroll
                for (int ni = 0; ni < 2; ++ni)
                    acc[mi][ni] = __builtin_amdgcn_mfma_f32_16x16x32_bf16(
                        af[mi][ks], bfr[ni][ks], acc[mi][ni], 0, 0, 0);
        __syncthreads();
        cur ^= 1;
    }

    // LDS-bounce epilogue: per-wave [32][33] fp32 scratch -> row-contiguous bf16 stores
    float* epi = (float*)lbase0 + w * 1056;    // 32*33 floats per wave
#pragma unroll
    for (int mi = 0; mi < 2; ++mi)
#pragma unroll
        for (int ni = 0; ni < 2; ++ni)
#pragma unroll
            for (int j = 0; j < 4; ++j) {
                int row = mi * 16 + (l >> 4) * 4 + j;
                int col = ni * 16 + (l & 15);
                epi[row * 33 + col] = acc[mi][ni][j];
            }
    int c = l & 31, half = l >> 5;
    u16x8 o0, o1;
#pragma unroll
    for (int q = 0; q < 8; ++q) o0[q] = f2bf(epi[c * 33 + half * 16 + q]);
#pragma unroll
    for (int q = 0; q < 8; ++q) o1[q] = f2bf(epi[c * 33 + half * 16 + 8 + q]);
    unsigned short* dst = xwT + (size_t)(m0 + wr * 32 + c) * NPq + n0 + wc * 32 + half * 16;
    *(u16x8*)dst = o0;
    *(u16x8*)(dst + 8) = o1;
}

// ---------------- out[b*95+nl][h] = sum_k A2b[b][nl][k] * Ychunk + root + bias
__global__ __launch_bounds__(256) void k_gemm2(const unsigned short* __restrict__ A2b,
                                               const unsigned short* __restrict__ xwT,
                                               const float* __restrict__ bias,
                                               float* __restrict__ out) {
    __shared__ char lds[2][30720];      // per buf: A 96x96 bf16 (18432) + Y 64x96 bf16 (12288)
    const int tid = threadIdx.x;
    const int b = blockIdx.x;
    const int h0 = blockIdx.y * 64;
    const int w = tid >> 6, l = tid & 63;
    const int wr = w >> 1, wc = w & 1;

    f32x4 acc[3][2];
#pragma unroll
    for (int i = 0; i < 3; ++i)
#pragma unroll
        for (int j = 0; j < 2; ++j) acc[i][j] = (f32x4)0.0f;

    auto stage = [&](int buf, int r) {
        char* base = &lds[buf][0];
#pragma unroll
        for (int i = 0; i < 5; ++i) {
            unsigned idx = tid + i * 256;
            if (idx < 1152) {
                unsigned row = idx / 12, u = idx - row * 12;
                unsigned usw = u ^ (row & 3);
                const unsigned short* g = A2b + ((size_t)b * 96 + row) * KAq + r * 96 + usw * 8;
                __builtin_amdgcn_global_load_lds((gu32*)g,
                    (lu32*)(unsigned int)(uintptr_t)(base + idx * 16), 16, 0, 0);
            }
        }
#pragma unroll
        for (int i = 0; i < 3; ++i) {
            unsigned idx = tid + i * 256;
            unsigned row = idx / 12, u = idx - row * 12;
            unsigned usw = u ^ (row & 3);
            const unsigned short* g = xwT + (size_t)(r * 256 + h0 + row) * NPq + b * 96 + usw * 8;
            __builtin_amdgcn_global_load_lds((gu32*)g,
                (lu32*)(unsigned int)(uintptr_t)(base + 18432 + idx * 16), 16, 0, 0);
        }
    };

    stage(0, 0);
    __syncthreads();
    int cur = 0;
    for (int r = 0; r < 5; ++r) {
        char* base = &lds[cur][0];
        if (r < 4) stage(cur ^ 1, r + 1);
        bf16x8 af[3], bfv[2];
#pragma unroll
        for (int ks = 0; ks < 3; ++ks) {
            int kb = ks * 64 + (l >> 4) * 16;
#pragma unroll
            for (int mi = 0; mi < 3; ++mi) {
                int row = wr * 48 + mi * 16 + (l & 15);
                af[mi] = *(const bf16x8*)(base + row * 192 + (kb ^ ((row & 3) << 4)));
            }
#pragma unroll
            for (int ni = 0; ni < 2; ++ni) {
                int row = wc * 32 + ni * 16 + (l & 15);
                bfv[ni] = *(const bf16x8*)(base + 18432 + row * 192 + (kb ^ ((row & 3) << 4)));
            }
#pragma unroll
            for (int mi = 0; mi < 3; ++mi)
#pragma unroll
                for (int ni = 0; ni < 2; ++ni)
                    acc[mi][ni] = __builtin_amdgcn_mfma_f32_16x16x32_bf16(
                        af[mi], bfv[ni], acc[mi][ni], 0, 0, 0);
        }
        __syncthreads();
        cur ^= 1;
    }

#pragma unroll
    for (int mi = 0; mi < 3; ++mi) {
        int mrow = wr * 48 + mi * 16 + (l >> 4) * 4;
#pragma unroll
        for (int ni = 0; ni < 2; ++ni) {
            int n = h0 + wc * 32 + ni * 16 + (l & 15);
            float bv = bias[n];
            ushort4 rt = *(const ushort4*)(xwT + (size_t)(Rq * 256 + n) * NPq + b * 96 + mrow);
#pragma unroll
            for (int j = 0; j < 4; ++j) {
                int m = mrow + j;
                float rv = bf2f(j == 0 ? rt.x : j == 1 ? rt.y : j == 2 ? rt.z : rt.w);
                if (m < NPGq)
                    out[((size_t)b * NPGq + m) * Hq + n] = acc[mi][ni][j] + rv + bv;
            }
        }
    }
}

extern "C" void kernel_launch(void* const* d_in, const int* in_sizes, int n_in,
                              void* d_out, int out_size, void* d_ws, size_t ws_size,
                              hipStream_t stream) {
    (void)in_sizes; (void)n_in; (void)out_size; (void)ws_size;
    const float* M     = (const float*)d_in[0];
    const float* x     = (const float*)d_in[1];
    const float* natt  = (const float*)d_in[2];
    const float* Ws    = (const float*)d_in[3];
    const float* bases = (const float*)d_in[4];
    const float* comp  = (const float*)d_in[5];
    const float* rootw = (const float*)d_in[6];
    const float* bias  = (const float*)d_in[7];
    const int* esrc    = (const int*)d_in[8];
    const int* edst    = (const int*)d_in[9];
    const int* etype   = (const int*)d_in[10];
    float* out = (float*)d_out;
    char* ws = (char*)d_ws;

    unsigned short* Wt  = (unsigned short*)(ws + 0);          //    786,432 B
    float* scale = (float*)(ws + 786432);                     //  2,073,600 B
    float* mxv   = (float*)(ws + 2860032);                    //     23,040 B
    float* den   = (float*)(ws + 2883072);                    //     23,040 B
    float* A2f   = (float*)(ws + 2906112);                    // 11,796,480 B
    unsigned short* A2b = (unsigned short*)(ws + 14702592);   //  5,898,240 B
    unsigned short* xb  = (unsigned short*)(ws + 20600832);   //  3,145,728 B
    unsigned short* xwT = (unsigned short*)(ws + 23746560);   // 18,874,368 B (total 42.6 MB)

    hipMemsetAsync(A2f, 0, 11796480, stream);
    k_wt<<<dim3(6, 8), 256, 0, stream>>>(bases, comp, rootw, Wt);
    k_scale<<<dim3(Bq * Tq), 128, 0, stream>>>(M, Ws, scale);
    k_stats<<<dim3((Bq * Tq + 255) / 256), 256, 0, stream>>>(scale, mxv, den);
    k_edges<<<dim3((Eq + 255) / 256), 256, 0, stream>>>(scale, mxv, den, natt,
                                                        esrc, edst, etype, A2f);
    k_a2bf<<<dim3((Bq * 96 * KAq / 8 + 255) / 256), 256, 0, stream>>>(A2f, A2b);
    k_xbf<<<dim3((NPq * 32 + 255) / 256), 256, 0, stream>>>(x, xb);
    k_gemm1<<<dim3(KKq / 64, NPq / 64), 256, 0, stream>>>(Wt, xb, xwT);
    k_gemm2<<<dim3(Bq, Hq / 64), 256, 0, stream>>>(A2b, xwT, bias, out);
}

// Round 4
// 84.528 us; speedup vs baseline: 4.0186x; 1.9014x over previous
//
#include <hip/hip_runtime.h>
#include <cstddef>
#include <cstdint>

#define Bq 64
#define Tq 90
#define Oq 5
#define Dq 256
#define Hq 256
#define EAq 4096
#define Rq 5
#define NBq 8
#define NPGq 95
#define Nq 6080           // B*NPG real nodes
#define NPq 6144          // padded node space: 64 graphs x 96
#define EPBq 4546         // EA + T*O
#define Eq 290944         // B*EPB
#define KKq 1536          // (R+1)*D rows of WT / xwT
#define KAq 480           // A2 cols: 5 relations x 96

typedef __attribute__((ext_vector_type(8))) short bf16x8;
typedef __attribute__((ext_vector_type(8))) unsigned short u16x8;
typedef __attribute__((ext_vector_type(4))) float f32x4;
typedef __attribute__((address_space(1))) const unsigned int gu32;
typedef __attribute__((address_space(3))) unsigned int lu32;

__device__ __forceinline__ unsigned short f2bf(float f) {
    unsigned u = __float_as_uint(f);
    unsigned r = (u + 0x7FFF + ((u >> 16) & 1)) >> 16;
    return (unsigned short)r;
}
__device__ __forceinline__ float bf2f(unsigned short s) {
    return __uint_as_float(((unsigned)s) << 16);
}

// ---------------- WT[kk][d] bf16: kk=r*256+h -> sum_nb comp[r][nb]*bases[nb][d][h]; kk=1280+h -> root[d][h]
__global__ __launch_bounds__(256) void k_wt(const float* __restrict__ bases,
                                            const float* __restrict__ comp,
                                            const float* __restrict__ rootw,
                                            unsigned short* __restrict__ Wt) {
    __shared__ float Ld[32][257];
    int rs = blockIdx.x;          // 0..5 (5 = root slice)
    int d0 = blockIdx.y * 32;
    int t = threadIdx.x;          // h
    float cmp[NBq];
    if (rs < Rq)
#pragma unroll
        for (int nb = 0; nb < NBq; ++nb) cmp[nb] = comp[rs * NBq + nb];
    for (int dl = 0; dl < 32; ++dl) {
        int d = d0 + dl;
        float v;
        if (rs < Rq) {
            v = 0.f;
#pragma unroll
            for (int nb = 0; nb < NBq; ++nb)
                v += cmp[nb] * bases[((size_t)nb * Dq + d) * Hq + t];
        } else {
            v = rootw[(size_t)d * Hq + t];
        }
        Ld[dl][t] = v;
    }
    __syncthreads();
    int c = t & 31, hg = t >> 5;
    for (int hh = 0; hh < 32; ++hh) {
        int h = hg * 32 + hh;
        Wt[(size_t)(rs * 256 + h) * Dq + d0 + c] = f2bf(Ld[c][h]);
    }
}

// ---------------- fused: P_b = M_b @ Ws^T (bf16 MFMA), column softmax, emit alphaT[b][s][t]
__global__ __launch_bounds__(256) void k_attn(const float* __restrict__ M,
                                              const float* __restrict__ Ws,
                                              float* __restrict__ alphaT) {
    __shared__ __attribute__((aligned(16))) char lds[99072];
    unsigned short* Mb = (unsigned short*)lds;           // [96][256] bf16, swizzled (48KB)
    unsigned short* Wb = (unsigned short*)(lds + 49152); // [96][256] bf16, swizzled (48KB)
    float* P   = (float*)lds;                            // [96][97] fp32 (reuses Mb region)
    float* mxs = (float*)(lds + 98304);                  // [96]
    float* rds = (float*)(lds + 98688);                  // [96]
    const int b = blockIdx.x;
    const int tid = threadIdx.x;

    // stage M[b] and Ws as bf16 with XOR swizzle; rows 90..95 zero
#pragma unroll
    for (int i = 0; i < 12; ++i) {
        int idx = tid + i * 256;            // 0..3071
        int row = idx >> 5, c = idx & 31;
        u16x8 pm, pw;
        if (row < Tq) {
            const float4* ms = (const float4*)(M + ((size_t)b * Tq + row) * Dq + c * 8);
            float4 a0 = ms[0], a1 = ms[1];
            pm[0] = f2bf(a0.x); pm[1] = f2bf(a0.y); pm[2] = f2bf(a0.z); pm[3] = f2bf(a0.w);
            pm[4] = f2bf(a1.x); pm[5] = f2bf(a1.y); pm[6] = f2bf(a1.z); pm[7] = f2bf(a1.w);
            const float4* ws = (const float4*)(Ws + (size_t)row * Dq + c * 8);
            float4 w0 = ws[0], w1 = ws[1];
            pw[0] = f2bf(w0.x); pw[1] = f2bf(w0.y); pw[2] = f2bf(w0.z); pw[3] = f2bf(w0.w);
            pw[4] = f2bf(w1.x); pw[5] = f2bf(w1.y); pw[6] = f2bf(w1.z); pw[7] = f2bf(w1.w);
        } else {
#pragma unroll
            for (int q = 0; q < 8; ++q) { pm[q] = 0; pw[q] = 0; }
        }
        int off = row * 512 + ((c * 16) ^ ((row & 7) << 4));
        *(u16x8*)((char*)Mb + off) = pm;
        *(u16x8*)((char*)Wb + off) = pw;
    }
    __syncthreads();

    // 96x96 MFMA: P[t][s] = sum_d Mb[t][d] * Wb[s][d]; 4 waves, each 48x48
    const int w = tid >> 6, l = tid & 63;
    const int wr = w >> 1, wc = w & 1;
    f32x4 acc[3][3];
#pragma unroll
    for (int i = 0; i < 3; ++i)
#pragma unroll
        for (int j = 0; j < 3; ++j) acc[i][j] = (f32x4)0.0f;
#pragma unroll
    for (int ks = 0; ks < 8; ++ks) {
        int kb = ks * 64 + (l >> 4) * 16;
        bf16x8 af[3], bfv[3];
#pragma unroll
        for (int mi = 0; mi < 3; ++mi) {
            int row = wr * 48 + mi * 16 + (l & 15);
            af[mi] = *(const bf16x8*)((char*)Mb + row * 512 + (kb ^ ((row & 7) << 4)));
        }
#pragma unroll
        for (int ni = 0; ni < 3; ++ni) {
            int row = wc * 48 + ni * 16 + (l & 15);
            bfv[ni] = *(const bf16x8*)((char*)Wb + row * 512 + (kb ^ ((row & 7) << 4)));
        }
#pragma unroll
        for (int mi = 0; mi < 3; ++mi)
#pragma unroll
            for (int ni = 0; ni < 3; ++ni)
                acc[mi][ni] = __builtin_amdgcn_mfma_f32_16x16x32_bf16(
                    af[mi], bfv[ni], acc[mi][ni], 0, 0, 0);
    }
    __syncthreads();   // all MFMA reads of Mb/Wb done; reuse region for P

#pragma unroll
    for (int mi = 0; mi < 3; ++mi)
#pragma unroll
        for (int ni = 0; ni < 3; ++ni)
#pragma unroll
            for (int j = 0; j < 4; ++j) {
                int rowp = wr * 48 + mi * 16 + (l >> 4) * 4 + j;
                int colp = wc * 48 + ni * 16 + (l & 15);
                P[rowp * 97 + colp] = acc[mi][ni][j];
            }
    __syncthreads();

    if (tid < 96) {
        float m = -1e30f;
        for (int t = 0; t < Tq; ++t) m = fmaxf(m, P[t * 97 + tid]);
        float s = 0.f;
        for (int t = 0; t < Tq; ++t) s += __expf(P[t * 97 + tid] - m);
        mxs[tid] = m;
        rds[tid] = 1.f / s;
    }
    __syncthreads();

#pragma unroll
    for (int i = 0; i < 36; ++i) {
        int idx = tid + i * 256;            // 0..9215
        int s = idx / 96, t = idx - s * 96;
        float v = (t < Tq) ? __expf(P[t * 97 + s] - mxs[s]) * rds[s] : 0.f;
        alphaT[((size_t)b * 96 + s) * 96 + t] = v;
    }
}

// ---------------- scatter scalar norms into A2f[b][dst][r*96+src]
__global__ void k_edges(const float* __restrict__ alphaT, const float* __restrict__ natt,
                        const int* __restrict__ esrc, const int* __restrict__ edst,
                        const int* __restrict__ etype, float* __restrict__ A2f) {
    int e = blockIdx.x * blockDim.x + threadIdx.x;
    if (e >= Eq) return;
    int b = e / EPBq, j = e % EPBq;
    float norm;
    int row, col;
    if (j < EAq) {
        int s  = esrc[(size_t)b * EAq + j];
        int dt = edst[(size_t)b * EAq + j];
        int r  = etype[(size_t)b * EAq + j];
        norm = alphaT[((size_t)b * 96 + s) * 96 + dt];
        row = dt;
        col = r * 96 + s;
    } else {
        int i = j - EAq;
        int t = i / Oq, o = i % Oq;
        norm = natt[(size_t)b * (Tq * Oq) + i];
        row = Tq + o;
        col = (Rq - 1) * 96 + t;
    }
    atomicAdd(&A2f[((size_t)b * 96 + row) * KAq + col], norm);
}

// ---------------- A2f fp32 -> A2b bf16
__global__ void k_a2bf(const float* __restrict__ A2f, unsigned short* __restrict__ A2b) {
    unsigned i = blockIdx.x * blockDim.x + threadIdx.x;   // over 64*96*480/8
    if (i >= (Bq * 96 * KAq) / 8) return;
    const float4* s4 = (const float4*)(A2f + (size_t)i * 8);
    float4 a = s4[0], c = s4[1];
    u16x8 pk;
    pk[0] = f2bf(a.x); pk[1] = f2bf(a.y); pk[2] = f2bf(a.z); pk[3] = f2bf(a.w);
    pk[4] = f2bf(c.x); pk[5] = f2bf(c.y); pk[6] = f2bf(c.z); pk[7] = f2bf(c.w);
    *(u16x8*)(A2b + (size_t)i * 8) = pk;
}

// ---------------- x fp32 [6080][256] -> xb bf16 [6144][256] (row n'=b*96+s, s=95 zero pad)
__global__ void k_xbf(const float* __restrict__ x, unsigned short* __restrict__ xb) {
    unsigned i = blockIdx.x * blockDim.x + threadIdx.x;   // over NPq*32 chunks of 8
    if (i >= NPq * 32) return;
    unsigned np = i >> 5, c = i & 31;
    unsigned s = np % 96;
    u16x8 pk;
    if (s == 95) {
#pragma unroll
        for (int q = 0; q < 8; ++q) pk[q] = 0;
    } else {
        unsigned node = np - np / 96;
        const float4* xs = (const float4*)(x + (size_t)node * Dq + c * 8);
        float4 a = xs[0], b2 = xs[1];
        pk[0] = f2bf(a.x);  pk[1] = f2bf(a.y);  pk[2] = f2bf(a.z);  pk[3] = f2bf(a.w);
        pk[4] = f2bf(b2.x); pk[5] = f2bf(b2.y); pk[6] = f2bf(b2.z); pk[7] = f2bf(b2.w);
    }
    *(u16x8*)(xb + (size_t)np * Dq + c * 8) = pk;
}

// ---------------- xwT[kk][n'] = sum_d WT[kk][d] * xb[n'][d]   (bf16 MFMA, 64x64, K=256, dbuf)
__global__ __launch_bounds__(256) void k_gemm1(const unsigned short* __restrict__ Wt,
                                               const unsigned short* __restrict__ xb,
                                               unsigned short* __restrict__ xwT) {
    __shared__ float4 lds4[2][1024];    // per buf: As 8KB @0, Bs 8KB @8192
    const int tid = threadIdx.x;
    const int m0 = blockIdx.x * 64, n0 = blockIdx.y * 64;
    const int w = tid >> 6, l = tid & 63;
    const int wr = w >> 1, wc = w & 1;
    const int srow = tid >> 3;
    const int sc = tid & 7;

    f32x4 acc[2][2];
#pragma unroll
    for (int i = 0; i < 2; ++i)
#pragma unroll
        for (int j = 0; j < 2; ++j) acc[i][j] = (f32x4)0.0f;

    char* const lbase0 = (char*)&lds4[0][0];
    char* const lbase1 = (char*)&lds4[1][0];

    auto stage = [&](char* base, int k0) {
#pragma unroll
        for (int i = 0; i < 2; ++i) {
            int row = i * 32 + srow;
            int csrc = sc ^ (row & 7);
            const unsigned short* g = Wt + (size_t)(m0 + row) * Dq + k0 + csrc * 8;
            char* ld = base + i * 4096 + w * 1024;
            __builtin_amdgcn_global_load_lds((gu32*)g, (lu32*)(unsigned int)(uintptr_t)ld, 16, 0, 0);
        }
#pragma unroll
        for (int i = 0; i < 2; ++i) {
            int row = i * 32 + srow;
            int csrc = sc ^ (row & 7);
            const unsigned short* g = xb + (size_t)(n0 + row) * Dq + k0 + csrc * 8;
            char* ld = base + 8192 + i * 4096 + w * 1024;
            __builtin_amdgcn_global_load_lds((gu32*)g, (lu32*)(unsigned int)(uintptr_t)ld, 16, 0, 0);
        }
    };

    stage(lbase0, 0);
    __syncthreads();

    int cur = 0;
    for (int t = 0; t < Dq / 64; ++t) {
        char* base = cur ? lbase1 : lbase0;
        if (t < Dq / 64 - 1) stage(cur ? lbase0 : lbase1, (t + 1) * 64);

        bf16x8 af[2][2], bfr[2][2];
#pragma unroll
        for (int ks = 0; ks < 2; ++ks) {
            int koff = ks * 64 + (l >> 4) * 16;
#pragma unroll
            for (int mi = 0; mi < 2; ++mi) {
                int row = wr * 32 + mi * 16 + (l & 15);
                af[mi][ks] = *(const bf16x8*)(base + row * 128 + (koff ^ ((row & 7) << 4)));
            }
#pragma unroll
            for (int ni = 0; ni < 2; ++ni) {
                int row = wc * 32 + ni * 16 + (l & 15);
                bfr[ni][ks] = *(const bf16x8*)(base + 8192 + row * 128 + (koff ^ ((row & 7) << 4)));
            }
        }
#pragma unroll
        for (int ks = 0; ks < 2; ++ks)
#pragma unroll
            for (int mi = 0; mi < 2; ++mi)
#pragma unroll
                for (int ni = 0; ni < 2; ++ni)
                    acc[mi][ni] = __builtin_amdgcn_mfma_f32_16x16x32_bf16(
                        af[mi][ks], bfr[ni][ks], acc[mi][ni], 0, 0, 0);
        __syncthreads();
        cur ^= 1;
    }

    // LDS-bounce epilogue: per-wave [32][33] fp32 scratch -> row-contiguous bf16 stores
    float* epi = (float*)lbase0 + w * 1056;    // 32*33 floats per wave
#pragma unroll
    for (int mi = 0; mi < 2; ++mi)
#pragma unroll
        for (int ni = 0; ni < 2; ++ni)
#pragma unroll
            for (int j = 0; j < 4; ++j) {
                int row = mi * 16 + (l >> 4) * 4 + j;
                int col = ni * 16 + (l & 15);
                epi[row * 33 + col] = acc[mi][ni][j];
            }
    int c = l & 31, half = l >> 5;
    u16x8 o0, o1;
#pragma unroll
    for (int q = 0; q < 8; ++q) o0[q] = f2bf(epi[c * 33 + half * 16 + q]);
#pragma unroll
    for (int q = 0; q < 8; ++q) o1[q] = f2bf(epi[c * 33 + half * 16 + 8 + q]);
    unsigned short* dst = xwT + (size_t)(m0 + wr * 32 + c) * NPq + n0 + wc * 32 + half * 16;
    *(u16x8*)dst = o0;
    *(u16x8*)(dst + 8) = o1;
}

// ---------------- out[b*95+nl][h] = sum_k A2b[b][nl][k] * Ychunk + root + bias
__global__ __launch_bounds__(256) void k_gemm2(const unsigned short* __restrict__ A2b,
                                               const unsigned short* __restrict__ xwT,
                                               const float* __restrict__ bias,
                                               float* __restrict__ out) {
    __shared__ char lds[2][30720];      // per buf: A 96x96 bf16 (18432) + Y 64x96 bf16 (12288)
    const int tid = threadIdx.x;
    const int b = blockIdx.x;
    const int h0 = blockIdx.y * 64;
    const int w = tid >> 6, l = tid & 63;
    const int wr = w >> 1, wc = w & 1;

    f32x4 acc[3][2];
#pragma unroll
    for (int i = 0; i < 3; ++i)
#pragma unroll
        for (int j = 0; j < 2; ++j) acc[i][j] = (f32x4)0.0f;

    auto stage = [&](int buf, int r) {
        char* base = &lds[buf][0];
#pragma unroll
        for (int i = 0; i < 5; ++i) {
            unsigned idx = tid + i * 256;
            if (idx < 1152) {
                unsigned row = idx / 12, u = idx - row * 12;
                unsigned usw = u ^ (row & 3);
                const unsigned short* g = A2b + ((size_t)b * 96 + row) * KAq + r * 96 + usw * 8;
                __builtin_amdgcn_global_load_lds((gu32*)g,
                    (lu32*)(unsigned int)(uintptr_t)(base + idx * 16), 16, 0, 0);
            }
        }
#pragma unroll
        for (int i = 0; i < 3; ++i) {
            unsigned idx = tid + i * 256;
            unsigned row = idx / 12, u = idx - row * 12;
            unsigned usw = u ^ (row & 3);
            const unsigned short* g = xwT + (size_t)(r * 256 + h0 + row) * NPq + b * 96 + usw * 8;
            __builtin_amdgcn_global_load_lds((gu32*)g,
                (lu32*)(unsigned int)(uintptr_t)(base + 18432 + idx * 16), 16, 0, 0);
        }
    };

    stage(0, 0);
    __syncthreads();
    int cur = 0;
    for (int r = 0; r < 5; ++r) {
        char* base = &lds[cur][0];
        if (r < 4) stage(cur ^ 1, r + 1);
        bf16x8 af[3], bfv[2];
#pragma unroll
        for (int ks = 0; ks < 3; ++ks) {
            int kb = ks * 64 + (l >> 4) * 16;
#pragma unroll
            for (int mi = 0; mi < 3; ++mi) {
                int row = wr * 48 + mi * 16 + (l & 15);
                af[mi] = *(const bf16x8*)(base + row * 192 + (kb ^ ((row & 3) << 4)));
            }
#pragma unroll
            for (int ni = 0; ni < 2; ++ni) {
                int row = wc * 32 + ni * 16 + (l & 15);
                bfv[ni] = *(const bf16x8*)(base + 18432 + row * 192 + (kb ^ ((row & 3) << 4)));
            }
#pragma unroll
            for (int mi = 0; mi < 3; ++mi)
#pragma unroll
                for (int ni = 0; ni < 2; ++ni)
                    acc[mi][ni] = __builtin_amdgcn_mfma_f32_16x16x32_bf16(
                        af[mi], bfv[ni], acc[mi][ni], 0, 0, 0);
        }
        __syncthreads();
        cur ^= 1;
    }

#pragma unroll
    for (int mi = 0; mi < 3; ++mi) {
        int mrow = wr * 48 + mi * 16 + (l >> 4) * 4;
#pragma unroll
        for (int ni = 0; ni < 2; ++ni) {
            int n = h0 + wc * 32 + ni * 16 + (l & 15);
            float bv = bias[n];
            ushort4 rt = *(const ushort4*)(xwT + (size_t)(Rq * 256 + n) * NPq + b * 96 + mrow);
#pragma unroll
            for (int j = 0; j < 4; ++j) {
                int m = mrow + j;
                float rv = bf2f(j == 0 ? rt.x : j == 1 ? rt.y : j == 2 ? rt.z : rt.w);
                if (m < NPGq)
                    out[((size_t)b * NPGq + m) * Hq + n] = acc[mi][ni][j] + rv + bv;
            }
        }
    }
}

extern "C" void kernel_launch(void* const* d_in, const int* in_sizes, int n_in,
                              void* d_out, int out_size, void* d_ws, size_t ws_size,
                              hipStream_t stream) {
    (void)in_sizes; (void)n_in; (void)out_size; (void)ws_size;
    const float* M     = (const float*)d_in[0];
    const float* x     = (const float*)d_in[1];
    const float* natt  = (const float*)d_in[2];
    const float* Ws    = (const float*)d_in[3];
    const float* bases = (const float*)d_in[4];
    const float* comp  = (const float*)d_in[5];
    const float* rootw = (const float*)d_in[6];
    const float* bias  = (const float*)d_in[7];
    const int* esrc    = (const int*)d_in[8];
    const int* edst    = (const int*)d_in[9];
    const int* etype   = (const int*)d_in[10];
    float* out = (float*)d_out;
    char* ws = (char*)d_ws;

    unsigned short* Wt  = (unsigned short*)(ws + 0);          //    786,432 B
    float* alphaT = (float*)(ws + 786432);                    //  2,359,296 B
    float* A2f   = (float*)(ws + 3145728);                    // 11,796,480 B
    unsigned short* A2b = (unsigned short*)(ws + 14942208);   //  5,898,240 B
    unsigned short* xb  = (unsigned short*)(ws + 20840448);   //  3,145,728 B
    unsigned short* xwT = (unsigned short*)(ws + 23986176);   // 18,874,368 B (total 42.9 MB)

    hipMemsetAsync(A2f, 0, 11796480, stream);
    k_wt<<<dim3(6, 8), 256, 0, stream>>>(bases, comp, rootw, Wt);
    k_attn<<<dim3(Bq), 256, 0, stream>>>(M, Ws, alphaT);
    k_edges<<<dim3((Eq + 255) / 256), 256, 0, stream>>>(alphaT, natt, esrc, edst, etype, A2f);
    k_a2bf<<<dim3((Bq * 96 * KAq / 8 + 255) / 256), 256, 0, stream>>>(A2f, A2b);
    k_xbf<<<dim3((NPq * 32 + 255) / 256), 256, 0, stream>>>(x, xb);
    k_gemm1<<<dim3(KKq / 64, NPq / 64), 256, 0, stream>>>(Wt, xb, xwT);
    k_gemm2<<<dim3(Bq, Hq / 64), 256, 0, stream>>>(A2b, xwT, bias, out);
}

// Round 5
// 80.245 us; speedup vs baseline: 4.2331x; 1.0534x over previous
//
#include <hip/hip_runtime.h>
#include <cstddef>
#include <cstdint>

#define Bq 64
#define Tq 90
#define Oq 5
#define Dq 256
#define Hq 256
#define EAq 4096
#define Rq 5
#define NBq 8
#define NPGq 95
#define Nq 6080           // B*NPG real nodes
#define NPq 6144          // padded node space: 64 graphs x 96
#define EPBq 4546         // EA + T*O
#define Eq 290944         // B*EPB
#define KKq 1536          // (R+1)*D rows of WT / xwT
#define KAq 480           // A2 cols: 5 relations x 96

typedef __attribute__((ext_vector_type(8))) short bf16x8;
typedef __attribute__((ext_vector_type(8))) unsigned short u16x8;
typedef __attribute__((ext_vector_type(4))) float f32x4;
typedef __attribute__((address_space(1))) const unsigned int gu32;
typedef __attribute__((address_space(3))) unsigned int lu32;

__device__ __forceinline__ unsigned short f2bf(float f) {
    unsigned u = __float_as_uint(f);
    unsigned r = (u + 0x7FFF + ((u >> 16) & 1)) >> 16;
    return (unsigned short)r;
}
__device__ __forceinline__ float bf2f(unsigned short s) {
    return __uint_as_float(((unsigned)s) << 16);
}

// ---------------- fused prep: blocks 0..2879 zero A2f (exact-fit float4), blocks 2880..3647 x->xb bf16
__global__ __launch_bounds__(256) void k_prep(const float* __restrict__ x,
                                              unsigned short* __restrict__ xb,
                                              float* __restrict__ A2f) {
    int blk = blockIdx.x;
    if (blk < 2880) {
        unsigned i = blk * 256 + threadIdx.x;       // 737280 float4s == 11,796,480 B
        ((float4*)A2f)[i] = make_float4(0.f, 0.f, 0.f, 0.f);
        return;
    }
    unsigned i = (blk - 2880) * 256 + threadIdx.x;  // over NPq*32 chunks of 8
    unsigned np = i >> 5, c = i & 31;
    unsigned s = np % 96;
    u16x8 pk;
    if (s == 95) {
#pragma unroll
        for (int q = 0; q < 8; ++q) pk[q] = 0;
    } else {
        unsigned node = np - np / 96;
        const float4* xs = (const float4*)(x + (size_t)node * Dq + c * 8);
        float4 a = xs[0], b2 = xs[1];
        pk[0] = f2bf(a.x);  pk[1] = f2bf(a.y);  pk[2] = f2bf(a.z);  pk[3] = f2bf(a.w);
        pk[4] = f2bf(b2.x); pk[5] = f2bf(b2.y); pk[6] = f2bf(b2.z); pk[7] = f2bf(b2.w);
    }
    *(u16x8*)(xb + (size_t)np * Dq + c * 8) = pk;
}

// ---------------- WT[kk][d] bf16: kk=r*256+h -> sum_nb comp[r][nb]*bases[nb][d][h]; kk=1280+h -> root[d][h]
__global__ __launch_bounds__(256) void k_wt(const float* __restrict__ bases,
                                            const float* __restrict__ comp,
                                            const float* __restrict__ rootw,
                                            unsigned short* __restrict__ Wt) {
    __shared__ float Ld[32][257];
    int rs = blockIdx.x;          // 0..5 (5 = root slice)
    int d0 = blockIdx.y * 32;
    int t = threadIdx.x;          // h
    float cmp[NBq];
    if (rs < Rq)
#pragma unroll
        for (int nb = 0; nb < NBq; ++nb) cmp[nb] = comp[rs * NBq + nb];
    for (int dl = 0; dl < 32; ++dl) {
        int d = d0 + dl;
        float v;
        if (rs < Rq) {
            v = 0.f;
#pragma unroll
            for (int nb = 0; nb < NBq; ++nb)
                v += cmp[nb] * bases[((size_t)nb * Dq + d) * Hq + t];
        } else {
            v = rootw[(size_t)d * Hq + t];
        }
        Ld[dl][t] = v;
    }
    __syncthreads();
    int c = t & 31, hg = t >> 5;
    for (int hh = 0; hh < 32; ++hh) {
        int h = hg * 32 + hh;
        Wt[(size_t)(rs * 256 + h) * Dq + d0 + c] = f2bf(Ld[c][h]);
    }
}

// ---------------- fused: P_b = M_b @ Ws^T (bf16 MFMA), column softmax, emit alphaT[b][s][t]
__global__ __launch_bounds__(256) void k_attn(const float* __restrict__ M,
                                              const float* __restrict__ Ws,
                                              float* __restrict__ alphaT) {
    __shared__ __attribute__((aligned(16))) char lds[99072];
    unsigned short* Mb = (unsigned short*)lds;           // [96][256] bf16, swizzled (48KB)
    unsigned short* Wb = (unsigned short*)(lds + 49152); // [96][256] bf16, swizzled (48KB)
    float* P   = (float*)lds;                            // [96][97] fp32 (reuses Mb region)
    float* mxs = (float*)(lds + 98304);                  // [96]
    float* rds = (float*)(lds + 98688);                  // [96]
    const int b = blockIdx.x;
    const int tid = threadIdx.x;

#pragma unroll
    for (int i = 0; i < 12; ++i) {
        int idx = tid + i * 256;            // 0..3071
        int row = idx >> 5, c = idx & 31;
        u16x8 pm, pw;
        if (row < Tq) {
            const float4* ms = (const float4*)(M + ((size_t)b * Tq + row) * Dq + c * 8);
            float4 a0 = ms[0], a1 = ms[1];
            pm[0] = f2bf(a0.x); pm[1] = f2bf(a0.y); pm[2] = f2bf(a0.z); pm[3] = f2bf(a0.w);
            pm[4] = f2bf(a1.x); pm[5] = f2bf(a1.y); pm[6] = f2bf(a1.z); pm[7] = f2bf(a1.w);
            const float4* ws = (const float4*)(Ws + (size_t)row * Dq + c * 8);
            float4 w0 = ws[0], w1 = ws[1];
            pw[0] = f2bf(w0.x); pw[1] = f2bf(w0.y); pw[2] = f2bf(w0.z); pw[3] = f2bf(w0.w);
            pw[4] = f2bf(w1.x); pw[5] = f2bf(w1.y); pw[6] = f2bf(w1.z); pw[7] = f2bf(w1.w);
        } else {
#pragma unroll
            for (int q = 0; q < 8; ++q) { pm[q] = 0; pw[q] = 0; }
        }
        int off = row * 512 + ((c * 16) ^ ((row & 7) << 4));
        *(u16x8*)((char*)Mb + off) = pm;
        *(u16x8*)((char*)Wb + off) = pw;
    }
    __syncthreads();

    const int w = tid >> 6, l = tid & 63;
    const int wr = w >> 1, wc = w & 1;
    f32x4 acc[3][3];
#pragma unroll
    for (int i = 0; i < 3; ++i)
#pragma unroll
        for (int j = 0; j < 3; ++j) acc[i][j] = (f32x4)0.0f;
#pragma unroll
    for (int ks = 0; ks < 8; ++ks) {
        int kb = ks * 64 + (l >> 4) * 16;
        bf16x8 af[3], bfv[3];
#pragma unroll
        for (int mi = 0; mi < 3; ++mi) {
            int row = wr * 48 + mi * 16 + (l & 15);
            af[mi] = *(const bf16x8*)((char*)Mb + row * 512 + (kb ^ ((row & 7) << 4)));
        }
#pragma unroll
        for (int ni = 0; ni < 3; ++ni) {
            int row = wc * 48 + ni * 16 + (l & 15);
            bfv[ni] = *(const bf16x8*)((char*)Wb + row * 512 + (kb ^ ((row & 7) << 4)));
        }
#pragma unroll
        for (int mi = 0; mi < 3; ++mi)
#pragma unroll
            for (int ni = 0; ni < 3; ++ni)
                acc[mi][ni] = __builtin_amdgcn_mfma_f32_16x16x32_bf16(
                    af[mi], bfv[ni], acc[mi][ni], 0, 0, 0);
    }
    __syncthreads();   // all MFMA reads of Mb/Wb done; reuse region for P

#pragma unroll
    for (int mi = 0; mi < 3; ++mi)
#pragma unroll
        for (int ni = 0; ni < 3; ++ni)
#pragma unroll
            for (int j = 0; j < 4; ++j) {
                int rowp = wr * 48 + mi * 16 + (l >> 4) * 4 + j;
                int colp = wc * 48 + ni * 16 + (l & 15);
                P[rowp * 97 + colp] = acc[mi][ni][j];
            }
    __syncthreads();

    if (tid < 96) {
        float m = -1e30f;
        for (int t = 0; t < Tq; ++t) m = fmaxf(m, P[t * 97 + tid]);
        float s = 0.f;
        for (int t = 0; t < Tq; ++t) s += __expf(P[t * 97 + tid] - m);
        mxs[tid] = m;
        rds[tid] = 1.f / s;
    }
    __syncthreads();

#pragma unroll
    for (int i = 0; i < 36; ++i) {
        int idx = tid + i * 256;            // 0..9215
        int s = idx / 96, t = idx - s * 96;
        float v = (t < Tq) ? __expf(P[t * 97 + s] - mxs[s]) * rds[s] : 0.f;
        alphaT[((size_t)b * 96 + s) * 96 + t] = v;
    }
}

// ---------------- scatter scalar norms into A2f[b][dst][r*96+src]
__global__ void k_edges(const float* __restrict__ alphaT, const float* __restrict__ natt,
                        const int* __restrict__ esrc, const int* __restrict__ edst,
                        const int* __restrict__ etype, float* __restrict__ A2f) {
    int e = blockIdx.x * blockDim.x + threadIdx.x;
    if (e >= Eq) return;
    int b = e / EPBq, j = e % EPBq;
    float norm;
    int row, col;
    if (j < EAq) {
        int s  = esrc[(size_t)b * EAq + j];
        int dt = edst[(size_t)b * EAq + j];
        int r  = etype[(size_t)b * EAq + j];
        norm = alphaT[((size_t)b * 96 + s) * 96 + dt];
        row = dt;
        col = r * 96 + s;
    } else {
        int i = j - EAq;
        int t = i / Oq, o = i % Oq;
        norm = natt[(size_t)b * (Tq * Oq) + i];
        row = Tq + o;
        col = (Rq - 1) * 96 + t;
    }
    atomicAdd(&A2f[((size_t)b * 96 + row) * KAq + col], norm);
}

// ---------------- xwT[kk][n'] = sum_d WT[kk][d] * xb[n'][d]   (bf16 MFMA, 64x64, K=256, dbuf)
__global__ __launch_bounds__(256) void k_gemm1(const unsigned short* __restrict__ Wt,
                                               const unsigned short* __restrict__ xb,
                                               unsigned short* __restrict__ xwT) {
    __shared__ float4 lds4[2][1024];    // per buf: As 8KB @0, Bs 8KB @8192
    const int tid = threadIdx.x;
    const int m0 = blockIdx.x * 64, n0 = blockIdx.y * 64;
    const int w = tid >> 6, l = tid & 63;
    const int wr = w >> 1, wc = w & 1;
    const int srow = tid >> 3;
    const int sc = tid & 7;

    f32x4 acc[2][2];
#pragma unroll
    for (int i = 0; i < 2; ++i)
#pragma unroll
        for (int j = 0; j < 2; ++j) acc[i][j] = (f32x4)0.0f;

    char* const lbase0 = (char*)&lds4[0][0];
    char* const lbase1 = (char*)&lds4[1][0];

    auto stage = [&](char* base, int k0) {
#pragma unroll
        for (int i = 0; i < 2; ++i) {
            int row = i * 32 + srow;
            int csrc = sc ^ (row & 7);
            const unsigned short* g = Wt + (size_t)(m0 + row) * Dq + k0 + csrc * 8;
            char* ld = base + i * 4096 + w * 1024;
            __builtin_amdgcn_global_load_lds((gu32*)g, (lu32*)(unsigned int)(uintptr_t)ld, 16, 0, 0);
        }
#pragma unroll
        for (int i = 0; i < 2; ++i) {
            int row = i * 32 + srow;
            int csrc = sc ^ (row & 7);
            const unsigned short* g = xb + (size_t)(n0 + row) * Dq + k0 + csrc * 8;
            char* ld = base + 8192 + i * 4096 + w * 1024;
            __builtin_amdgcn_global_load_lds((gu32*)g, (lu32*)(unsigned int)(uintptr_t)ld, 16, 0, 0);
        }
    };

    stage(lbase0, 0);
    __syncthreads();

    int cur = 0;
    for (int t = 0; t < Dq / 64; ++t) {
        char* base = cur ? lbase1 : lbase0;
        if (t < Dq / 64 - 1) stage(cur ? lbase0 : lbase1, (t + 1) * 64);

        bf16x8 af[2][2], bfr[2][2];
#pragma unroll
        for (int ks = 0; ks < 2; ++ks) {
            int koff = ks * 64 + (l >> 4) * 16;
#pragma unroll
            for (int mi = 0; mi < 2; ++mi) {
                int row = wr * 32 + mi * 16 + (l & 15);
                af[mi][ks] = *(const bf16x8*)(base + row * 128 + (koff ^ ((row & 7) << 4)));
            }
#pragma unroll
            for (int ni = 0; ni < 2; ++ni) {
                int row = wc * 32 + ni * 16 + (l & 15);
                bfr[ni][ks] = *(const bf16x8*)(base + 8192 + row * 128 + (koff ^ ((row & 7) << 4)));
            }
        }
#pragma unroll
        for (int ks = 0; ks < 2; ++ks)
#pragma unroll
            for (int mi = 0; mi < 2; ++mi)
#pragma unroll
                for (int ni = 0; ni < 2; ++ni)
                    acc[mi][ni] = __builtin_amdgcn_mfma_f32_16x16x32_bf16(
                        af[mi][ks], bfr[ni][ks], acc[mi][ni], 0, 0, 0);
        __syncthreads();
        cur ^= 1;
    }

    // LDS-bounce epilogue: per-wave [32][33] fp32 scratch -> row-contiguous bf16 stores
    float* epi = (float*)lbase0 + w * 1056;    // 32*33 floats per wave
#pragma unroll
    for (int mi = 0; mi < 2; ++mi)
#pragma unroll
        for (int ni = 0; ni < 2; ++ni)
#pragma unroll
            for (int j = 0; j < 4; ++j) {
                int row = mi * 16 + (l >> 4) * 4 + j;
                int col = ni * 16 + (l & 15);
                epi[row * 33 + col] = acc[mi][ni][j];
            }
    int c = l & 31, half = l >> 5;
    u16x8 o0, o1;
#pragma unroll
    for (int q = 0; q < 8; ++q) o0[q] = f2bf(epi[c * 33 + half * 16 + q]);
#pragma unroll
    for (int q = 0; q < 8; ++q) o1[q] = f2bf(epi[c * 33 + half * 16 + 8 + q]);
    unsigned short* dst = xwT + (size_t)(m0 + wr * 32 + c) * NPq + n0 + wc * 32 + half * 16;
    *(u16x8*)dst = o0;
    *(u16x8*)(dst + 8) = o1;
}

// ---------------- out[b*95+nl][h] = sum_k A2(fp32->bf16) * Ychunk + root + bias
__global__ __launch_bounds__(256) void k_gemm2(const float* __restrict__ A2f,
                                               const unsigned short* __restrict__ xwT,
                                               const float* __restrict__ bias,
                                               float* __restrict__ out) {
    __shared__ char lds[2][30720];      // per buf: A 96x96 bf16 (18432) + Y 64x96 bf16 (12288)
    const int tid = threadIdx.x;
    const int b = blockIdx.x;
    const int h0 = blockIdx.y * 64;
    const int w = tid >> 6, l = tid & 63;
    const int wr = w >> 1, wc = w & 1;

    f32x4 acc[3][2];
#pragma unroll
    for (int i = 0; i < 3; ++i)
#pragma unroll
        for (int j = 0; j < 2; ++j) acc[i][j] = (f32x4)0.0f;

    // reg-staged A: load fp32 chunks for relation r into registers
    auto loadA = [&](int r, float4 (&rg)[5][2]) {
#pragma unroll
        for (int i = 0; i < 5; ++i) {
            unsigned idx = tid + i * 256;
            if (idx < 1152) {
                unsigned row = idx / 12, u = idx - row * 12;
                const float4* s4 = (const float4*)(A2f + ((size_t)b * 96 + row) * KAq + r * 96 + u * 8);
                rg[i][0] = s4[0];
                rg[i][1] = s4[1];
            }
        }
    };
    auto writeA = [&](int buf, float4 (&rg)[5][2]) {
        char* base = &lds[buf][0];
#pragma unroll
        for (int i = 0; i < 5; ++i) {
            unsigned idx = tid + i * 256;
            if (idx < 1152) {
                unsigned row = idx / 12, u = idx - row * 12;
                u16x8 pk;
                pk[0] = f2bf(rg[i][0].x); pk[1] = f2bf(rg[i][0].y);
                pk[2] = f2bf(rg[i][0].z); pk[3] = f2bf(rg[i][0].w);
                pk[4] = f2bf(rg[i][1].x); pk[5] = f2bf(rg[i][1].y);
                pk[6] = f2bf(rg[i][1].z); pk[7] = f2bf(rg[i][1].w);
                unsigned usw = u ^ (row & 3);
                *(u16x8*)(base + row * 192 + usw * 16) = pk;
            }
        }
    };
    auto stageY = [&](int buf, int r) {
        char* base = &lds[buf][0];
#pragma unroll
        for (int i = 0; i < 3; ++i) {
            unsigned idx = tid + i * 256;
            unsigned row = idx / 12, u = idx - row * 12;
            unsigned usw = u ^ (row & 3);
            const unsigned short* g = xwT + (size_t)(r * 256 + h0 + row) * NPq + b * 96 + usw * 8;
            __builtin_amdgcn_global_load_lds((gu32*)g,
                (lu32*)(unsigned int)(uintptr_t)(base + 18432 + idx * 16), 16, 0, 0);
        }
    };

    float4 rgA[5][2], rgB[5][2];
    loadA(0, rgA);
    writeA(0, rgA);
    stageY(0, 0);
    __syncthreads();
    int cur = 0;
    for (int r = 0; r < 5; ++r) {
        char* base = &lds[cur][0];
        if (r < 4) { loadA(r + 1, rgB); stageY(cur ^ 1, r + 1); }
        bf16x8 af[3], bfv[2];
#pragma unroll
        for (int ks = 0; ks < 3; ++ks) {
            int kb = ks * 64 + (l >> 4) * 16;
#pragma unroll
            for (int mi = 0; mi < 3; ++mi) {
                int row = wr * 48 + mi * 16 + (l & 15);
                af[mi] = *(const bf16x8*)(base + row * 192 + (kb ^ ((row & 3) << 4)));
            }
#pragma unroll
            for (int ni = 0; ni < 2; ++ni) {
                int row = wc * 32 + ni * 16 + (l & 15);
                bfv[ni] = *(const bf16x8*)(base + 18432 + row * 192 + (kb ^ ((row & 3) << 4)));
            }
#pragma unroll
            for (int mi = 0; mi < 3; ++mi)
#pragma unroll
                for (int ni = 0; ni < 2; ++ni)
                    acc[mi][ni] = __builtin_amdgcn_mfma_f32_16x16x32_bf16(
                        af[mi], bfv[ni], acc[mi][ni], 0, 0, 0);
        }
        if (r < 4) writeA(cur ^ 1, rgB);   // cvt+ds_write after MFMAs: loads overlapped compute
        __syncthreads();
        cur ^= 1;
#pragma unroll
        for (int i = 0; i < 5; ++i) { rgA[i][0] = rgB[i][0]; rgA[i][1] = rgB[i][1]; }
        (void)rgA;
    }

#pragma unroll
    for (int mi = 0; mi < 3; ++mi) {
        int mrow = wr * 48 + mi * 16 + (l >> 4) * 4;
#pragma unroll
        for (int ni = 0; ni < 2; ++ni) {
            int n = h0 + wc * 32 + ni * 16 + (l & 15);
            float bv = bias[n];
            ushort4 rt = *(const ushort4*)(xwT + (size_t)(Rq * 256 + n) * NPq + b * 96 + mrow);
#pragma unroll
            for (int j = 0; j < 4; ++j) {
                int m = mrow + j;
                float rv = bf2f(j == 0 ? rt.x : j == 1 ? rt.y : j == 2 ? rt.z : rt.w);
                if (m < NPGq)
                    out[((size_t)b * NPGq + m) * Hq + n] = acc[mi][ni][j] + rv + bv;
            }
        }
    }
}

extern "C" void kernel_launch(void* const* d_in, const int* in_sizes, int n_in,
                              void* d_out, int out_size, void* d_ws, size_t ws_size,
                              hipStream_t stream) {
    (void)in_sizes; (void)n_in; (void)out_size; (void)ws_size;
    const float* M     = (const float*)d_in[0];
    const float* x     = (const float*)d_in[1];
    const float* natt  = (const float*)d_in[2];
    const float* Ws    = (const float*)d_in[3];
    const float* bases = (const float*)d_in[4];
    const float* comp  = (const float*)d_in[5];
    const float* rootw = (const float*)d_in[6];
    const float* bias  = (const float*)d_in[7];
    const int* esrc    = (const int*)d_in[8];
    const int* edst    = (const int*)d_in[9];
    const int* etype   = (const int*)d_in[10];
    float* out = (float*)d_out;
    char* ws = (char*)d_ws;

    unsigned short* Wt  = (unsigned short*)(ws + 0);          //    786,432 B
    float* alphaT = (float*)(ws + 786432);                    //  2,359,296 B
    float* A2f   = (float*)(ws + 3145728);                    // 11,796,480 B
    unsigned short* xb  = (unsigned short*)(ws + 14942208);   //  3,145,728 B
    unsigned short* xwT = (unsigned short*)(ws + 18087936);   // 18,874,368 B (total ~37 MB)

    k_prep<<<dim3(3648), 256, 0, stream>>>(x, xb, A2f);
    k_wt<<<dim3(6, 8), 256, 0, stream>>>(bases, comp, rootw, Wt);
    k_attn<<<dim3(Bq), 256, 0, stream>>>(M, Ws, alphaT);
    k_edges<<<dim3((Eq + 255) / 256), 256, 0, stream>>>(alphaT, natt, esrc, edst, etype, A2f);
    k_gemm1<<<dim3(KKq / 64, NPq / 64), 256, 0, stream>>>(Wt, xb, xwT);
    k_gemm2<<<dim3(Bq, Hq / 64), 256, 0, stream>>>(A2f, xwT, bias, out);
}

// Round 6
// 73.570 us; speedup vs baseline: 4.6172x; 1.0907x over previous
//
#include <hip/hip_runtime.h>
#include <cstddef>
#include <cstdint>

#define Bq 64
#define Tq 90
#define Oq 5
#define Dq 256
#define Hq 256
#define EAq 4096
#define Rq 5
#define NBq 8
#define NPGq 95
#define Nq 6080           // B*NPG real nodes
#define NPq 6144          // padded node space: 64 graphs x 96
#define EPBq 4546         // EA + T*O
#define Eq 290944         // B*EPB
#define KKq 1536          // (R+1)*D rows of WT / xwT
#define KAq 480           // A2 cols: 5 relations x 96

typedef __attribute__((ext_vector_type(8))) short bf16x8;
typedef __attribute__((ext_vector_type(8))) unsigned short u16x8;
typedef __attribute__((ext_vector_type(4))) float f32x4;
typedef __attribute__((address_space(1))) const unsigned int gu32;
typedef __attribute__((address_space(3))) unsigned int lu32;

__device__ __forceinline__ unsigned short f2bf(float f) {
    unsigned u = __float_as_uint(f);
    unsigned r = (u + 0x7FFF + ((u >> 16) & 1)) >> 16;
    return (unsigned short)r;
}
__device__ __forceinline__ float bf2f(unsigned short s) {
    return __uint_as_float(((unsigned)s) << 16);
}

// ---------------- fused prep:
// blocks 0..2879: zero A2f; 2880..3647: x->xb bf16; 3648..3695: Wt compute
__global__ __launch_bounds__(256) void k_prep(const float* __restrict__ x,
                                              const float* __restrict__ bases,
                                              const float* __restrict__ comp,
                                              const float* __restrict__ rootw,
                                              unsigned short* __restrict__ xb,
                                              unsigned short* __restrict__ Wt,
                                              float* __restrict__ A2f) {
    __shared__ float Ld[32][257];
    int blk = blockIdx.x;
    if (blk < 2880) {
        unsigned i = blk * 256 + threadIdx.x;       // 737280 float4s == 11,796,480 B
        ((float4*)A2f)[i] = make_float4(0.f, 0.f, 0.f, 0.f);
        return;
    }
    if (blk < 3648) {
        unsigned i = (blk - 2880) * 256 + threadIdx.x;  // over NPq*32 chunks of 8
        unsigned np = i >> 5, c = i & 31;
        unsigned s = np % 96;
        u16x8 pk;
        if (s == 95) {
#pragma unroll
            for (int q = 0; q < 8; ++q) pk[q] = 0;
        } else {
            unsigned node = np - np / 96;
            const float4* xs = (const float4*)(x + (size_t)node * Dq + c * 8);
            float4 a = xs[0], b2 = xs[1];
            pk[0] = f2bf(a.x);  pk[1] = f2bf(a.y);  pk[2] = f2bf(a.z);  pk[3] = f2bf(a.w);
            pk[4] = f2bf(b2.x); pk[5] = f2bf(b2.y); pk[6] = f2bf(b2.z); pk[7] = f2bf(b2.w);
        }
        *(u16x8*)(xb + (size_t)np * Dq + c * 8) = pk;
        return;
    }
    // Wt: WT[kk][d] bf16; kk=r*256+h or 1280+h (root)
    int wblk = blk - 3648;            // 0..47
    int rs = wblk >> 3;               // 0..5
    int d0 = (wblk & 7) * 32;
    int t = threadIdx.x;              // h
    float cmp[NBq];
    if (rs < Rq)
#pragma unroll
        for (int nb = 0; nb < NBq; ++nb) cmp[nb] = comp[rs * NBq + nb];
    for (int dl = 0; dl < 32; ++dl) {
        int d = d0 + dl;
        float v;
        if (rs < Rq) {
            v = 0.f;
#pragma unroll
            for (int nb = 0; nb < NBq; ++nb)
                v += cmp[nb] * bases[((size_t)nb * Dq + d) * Hq + t];
        } else {
            v = rootw[(size_t)d * Hq + t];
        }
        Ld[dl][t] = v;
    }
    __syncthreads();
    int c = t & 31, hg = t >> 5;
    for (int hh = 0; hh < 32; ++hh) {
        int h = hg * 32 + hh;
        Wt[(size_t)(rs * 256 + h) * Dq + d0 + c] = f2bf(Ld[c][h]);
    }
}

// ---------------- fused: P_b = M_b @ Ws^T (bf16 MFMA), column softmax stats,
//                  then scatter edge norms straight into A2f[b] (atomics for attn
//                  edges, plain stores for tag edges; rows disjoint)
__global__ __launch_bounds__(256) void k_attn(const float* __restrict__ M,
                                              const float* __restrict__ Ws,
                                              const float* __restrict__ natt,
                                              const int* __restrict__ esrc,
                                              const int* __restrict__ edst,
                                              const int* __restrict__ etype,
                                              float* __restrict__ A2f) {
    __shared__ __attribute__((aligned(16))) char lds[99072];
    unsigned short* Mb = (unsigned short*)lds;           // [96][256] bf16, swizzled (48KB)
    unsigned short* Wb = (unsigned short*)(lds + 49152); // [96][256] bf16, swizzled (48KB)
    float* P   = (float*)lds;                            // [96][97] fp32 (reuses Mb region)
    float* mxs = (float*)(lds + 98304);                  // [96]
    float* rds = (float*)(lds + 98688);                  // [96]
    const int b = blockIdx.x;
    const int tid = threadIdx.x;

#pragma unroll
    for (int i = 0; i < 12; ++i) {
        int idx = tid + i * 256;            // 0..3071
        int row = idx >> 5, c = idx & 31;
        u16x8 pm, pw;
        if (row < Tq) {
            const float4* ms = (const float4*)(M + ((size_t)b * Tq + row) * Dq + c * 8);
            float4 a0 = ms[0], a1 = ms[1];
            pm[0] = f2bf(a0.x); pm[1] = f2bf(a0.y); pm[2] = f2bf(a0.z); pm[3] = f2bf(a0.w);
            pm[4] = f2bf(a1.x); pm[5] = f2bf(a1.y); pm[6] = f2bf(a1.z); pm[7] = f2bf(a1.w);
            const float4* ws = (const float4*)(Ws + (size_t)row * Dq + c * 8);
            float4 w0 = ws[0], w1 = ws[1];
            pw[0] = f2bf(w0.x); pw[1] = f2bf(w0.y); pw[2] = f2bf(w0.z); pw[3] = f2bf(w0.w);
            pw[4] = f2bf(w1.x); pw[5] = f2bf(w1.y); pw[6] = f2bf(w1.z); pw[7] = f2bf(w1.w);
        } else {
#pragma unroll
            for (int q = 0; q < 8; ++q) { pm[q] = 0; pw[q] = 0; }
        }
        int off = row * 512 + ((c * 16) ^ ((row & 7) << 4));
        *(u16x8*)((char*)Mb + off) = pm;
        *(u16x8*)((char*)Wb + off) = pw;
    }
    __syncthreads();

    const int w = tid >> 6, l = tid & 63;
    const int wr = w >> 1, wc = w & 1;
    f32x4 acc[3][3];
#pragma unroll
    for (int i = 0; i < 3; ++i)
#pragma unroll
        for (int j = 0; j < 3; ++j) acc[i][j] = (f32x4)0.0f;
#pragma unroll
    for (int ks = 0; ks < 8; ++ks) {
        int kb = ks * 64 + (l >> 4) * 16;
        bf16x8 af[3], bfv[3];
#pragma unroll
        for (int mi = 0; mi < 3; ++mi) {
            int row = wr * 48 + mi * 16 + (l & 15);
            af[mi] = *(const bf16x8*)((char*)Mb + row * 512 + (kb ^ ((row & 7) << 4)));
        }
#pragma unroll
        for (int ni = 0; ni < 3; ++ni) {
            int row = wc * 48 + ni * 16 + (l & 15);
            bfv[ni] = *(const bf16x8*)((char*)Wb + row * 512 + (kb ^ ((row & 7) << 4)));
        }
#pragma unroll
        for (int mi = 0; mi < 3; ++mi)
#pragma unroll
            for (int ni = 0; ni < 3; ++ni)
                acc[mi][ni] = __builtin_amdgcn_mfma_f32_16x16x32_bf16(
                    af[mi], bfv[ni], acc[mi][ni], 0, 0, 0);
    }
    __syncthreads();   // all MFMA reads of Mb/Wb done; reuse region for P

#pragma unroll
    for (int mi = 0; mi < 3; ++mi)
#pragma unroll
        for (int ni = 0; ni < 3; ++ni)
#pragma unroll
            for (int j = 0; j < 4; ++j) {
                int rowp = wr * 48 + mi * 16 + (l >> 4) * 4 + j;
                int colp = wc * 48 + ni * 16 + (l & 15);
                P[rowp * 97 + colp] = acc[mi][ni][j];
            }
    __syncthreads();

    if (tid < 96) {
        float m = -1e30f;
        for (int t = 0; t < Tq; ++t) m = fmaxf(m, P[t * 97 + tid]);
        float s = 0.f;
        for (int t = 0; t < Tq; ++t) s += __expf(P[t * 97 + tid] - m);
        mxs[tid] = m;
        rds[tid] = 1.f / s;
    }
    __syncthreads();

    // edge scatter for this graph (4546 edges)
    for (int j = tid; j < EPBq; j += 256) {
        if (j < EAq) {
            int s  = esrc[(size_t)b * EAq + j];
            int dt = edst[(size_t)b * EAq + j];
            int r  = etype[(size_t)b * EAq + j];
            float v = __expf(P[dt * 97 + s] - mxs[s]) * rds[s];
            atomicAdd(&A2f[((size_t)b * 96 + dt) * KAq + r * 96 + s], v);
        } else {
            int i = j - EAq;
            int t = i / Oq, o = i % Oq;
            A2f[((size_t)b * 96 + Tq + o) * KAq + (Rq - 1) * 96 + t] =
                natt[(size_t)b * (Tq * Oq) + i];
        }
    }
}

// ---------------- A2f fp32 -> A2b bf16
__global__ void k_a2bf(const float* __restrict__ A2f, unsigned short* __restrict__ A2b) {
    unsigned i = blockIdx.x * blockDim.x + threadIdx.x;   // over 64*96*480/8
    if (i >= (Bq * 96 * KAq) / 8) return;
    const float4* s4 = (const float4*)(A2f + (size_t)i * 8);
    float4 a = s4[0], c = s4[1];
    u16x8 pk;
    pk[0] = f2bf(a.x); pk[1] = f2bf(a.y); pk[2] = f2bf(a.z); pk[3] = f2bf(a.w);
    pk[4] = f2bf(c.x); pk[5] = f2bf(c.y); pk[6] = f2bf(c.z); pk[7] = f2bf(c.w);
    *(u16x8*)(A2b + (size_t)i * 8) = pk;
}

// ---------------- xwT[kk][n'] = sum_d WT[kk][d] * xb[n'][d]   (bf16 MFMA, 64x64, K=256, dbuf)
__global__ __launch_bounds__(256) void k_gemm1(const unsigned short* __restrict__ Wt,
                                               const unsigned short* __restrict__ xb,
                                               unsigned short* __restrict__ xwT) {
    __shared__ float4 lds4[2][1024];    // per buf: As 8KB @0, Bs 8KB @8192
    const int tid = threadIdx.x;
    const int m0 = blockIdx.x * 64, n0 = blockIdx.y * 64;
    const int w = tid >> 6, l = tid & 63;
    const int wr = w >> 1, wc = w & 1;
    const int srow = tid >> 3;
    const int sc = tid & 7;

    f32x4 acc[2][2];
#pragma unroll
    for (int i = 0; i < 2; ++i)
#pragma unroll
        for (int j = 0; j < 2; ++j) acc[i][j] = (f32x4)0.0f;

    char* const lbase0 = (char*)&lds4[0][0];
    char* const lbase1 = (char*)&lds4[1][0];

    auto stage = [&](char* base, int k0) {
#pragma unroll
        for (int i = 0; i < 2; ++i) {
            int row = i * 32 + srow;
            int csrc = sc ^ (row & 7);
            const unsigned short* g = Wt + (size_t)(m0 + row) * Dq + k0 + csrc * 8;
            char* ld = base + i * 4096 + w * 1024;
            __builtin_amdgcn_global_load_lds((gu32*)g, (lu32*)(unsigned int)(uintptr_t)ld, 16, 0, 0);
        }
#pragma unroll
        for (int i = 0; i < 2; ++i) {
            int row = i * 32 + srow;
            int csrc = sc ^ (row & 7);
            const unsigned short* g = xb + (size_t)(n0 + row) * Dq + k0 + csrc * 8;
            char* ld = base + 8192 + i * 4096 + w * 1024;
            __builtin_amdgcn_global_load_lds((gu32*)g, (lu32*)(unsigned int)(uintptr_t)ld, 16, 0, 0);
        }
    };

    stage(lbase0, 0);
    __syncthreads();

    int cur = 0;
    for (int t = 0; t < Dq / 64; ++t) {
        char* base = cur ? lbase1 : lbase0;
        if (t < Dq / 64 - 1) stage(cur ? lbase0 : lbase1, (t + 1) * 64);

        bf16x8 af[2][2], bfr[2][2];
#pragma unroll
        for (int ks = 0; ks < 2; ++ks) {
            int koff = ks * 64 + (l >> 4) * 16;
#pragma unroll
            for (int mi = 0; mi < 2; ++mi) {
                int row = wr * 32 + mi * 16 + (l & 15);
                af[mi][ks] = *(const bf16x8*)(base + row * 128 + (koff ^ ((row & 7) << 4)));
            }
#pragma unroll
            for (int ni = 0; ni < 2; ++ni) {
                int row = wc * 32 + ni * 16 + (l & 15);
                bfr[ni][ks] = *(const bf16x8*)(base + 8192 + row * 128 + (koff ^ ((row & 7) << 4)));
            }
        }
#pragma unroll
        for (int ks = 0; ks < 2; ++ks)
#pragma unroll
            for (int mi = 0; mi < 2; ++mi)
#pragma unroll
                for (int ni = 0; ni < 2; ++ni)
                    acc[mi][ni] = __builtin_amdgcn_mfma_f32_16x16x32_bf16(
                        af[mi][ks], bfr[ni][ks], acc[mi][ni], 0, 0, 0);
        __syncthreads();
        cur ^= 1;
    }

    // LDS-bounce epilogue: per-wave [32][33] fp32 scratch -> row-contiguous bf16 stores
    float* epi = (float*)lbase0 + w * 1056;    // 32*33 floats per wave
#pragma unroll
    for (int mi = 0; mi < 2; ++mi)
#pragma unroll
        for (int ni = 0; ni < 2; ++ni)
#pragma unroll
            for (int j = 0; j < 4; ++j) {
                int row = mi * 16 + (l >> 4) * 4 + j;
                int col = ni * 16 + (l & 15);
                epi[row * 33 + col] = acc[mi][ni][j];
            }
    int c = l & 31, half = l >> 5;
    u16x8 o0, o1;
#pragma unroll
    for (int q = 0; q < 8; ++q) o0[q] = f2bf(epi[c * 33 + half * 16 + q]);
#pragma unroll
    for (int q = 0; q < 8; ++q) o1[q] = f2bf(epi[c * 33 + half * 16 + 8 + q]);
    unsigned short* dst = xwT + (size_t)(m0 + wr * 32 + c) * NPq + n0 + wc * 32 + half * 16;
    *(u16x8*)dst = o0;
    *(u16x8*)(dst + 8) = o1;
}

// ---------------- out[b*95+nl][h] = sum_k A2b[b][nl][k] * Ychunk + root + bias
__global__ __launch_bounds__(256) void k_gemm2(const unsigned short* __restrict__ A2b,
                                               const unsigned short* __restrict__ xwT,
                                               const float* __restrict__ bias,
                                               float* __restrict__ out) {
    __shared__ char lds[2][30720];      // per buf: A 96x96 bf16 (18432) + Y 64x96 bf16 (12288)
    const int tid = threadIdx.x;
    const int b = blockIdx.x;
    const int h0 = blockIdx.y * 64;
    const int w = tid >> 6, l = tid & 63;
    const int wr = w >> 1, wc = w & 1;

    f32x4 acc[3][2];
#pragma unroll
    for (int i = 0; i < 3; ++i)
#pragma unroll
        for (int j = 0; j < 2; ++j) acc[i][j] = (f32x4)0.0f;

    auto stage = [&](int buf, int r) {
        char* base = &lds[buf][0];
#pragma unroll
        for (int i = 0; i < 5; ++i) {
            unsigned idx = tid + i * 256;
            if (idx < 1152) {
                unsigned row = idx / 12, u = idx - row * 12;
                unsigned usw = u ^ (row & 3);
                const unsigned short* g = A2b + ((size_t)b * 96 + row) * KAq + r * 96 + usw * 8;
                __builtin_amdgcn_global_load_lds((gu32*)g,
                    (lu32*)(unsigned int)(uintptr_t)(base + idx * 16), 16, 0, 0);
            }
        }
#pragma unroll
        for (int i = 0; i < 3; ++i) {
            unsigned idx = tid + i * 256;
            unsigned row = idx / 12, u = idx - row * 12;
            unsigned usw = u ^ (row & 3);
            const unsigned short* g = xwT + (size_t)(r * 256 + h0 + row) * NPq + b * 96 + usw * 8;
            __builtin_amdgcn_global_load_lds((gu32*)g,
                (lu32*)(unsigned int)(uintptr_t)(base + 18432 + idx * 16), 16, 0, 0);
        }
    };

    stage(0, 0);
    __syncthreads();
    int cur = 0;
    for (int r = 0; r < 5; ++r) {
        char* base = &lds[cur][0];
        if (r < 4) stage(cur ^ 1, r + 1);
        bf16x8 af[3], bfv[2];
#pragma unroll
        for (int ks = 0; ks < 3; ++ks) {
            int kb = ks * 64 + (l >> 4) * 16;
#pragma unroll
            for (int mi = 0; mi < 3; ++mi) {
                int row = wr * 48 + mi * 16 + (l & 15);
                af[mi] = *(const bf16x8*)(base + row * 192 + (kb ^ ((row & 3) << 4)));
            }
#pragma unroll
            for (int ni = 0; ni < 2; ++ni) {
                int row = wc * 32 + ni * 16 + (l & 15);
                bfv[ni] = *(const bf16x8*)(base + 18432 + row * 192 + (kb ^ ((row & 3) << 4)));
            }
#pragma unroll
            for (int mi = 0; mi < 3; ++mi)
#pragma unroll
                for (int ni = 0; ni < 2; ++ni)
                    acc[mi][ni] = __builtin_amdgcn_mfma_f32_16x16x32_bf16(
                        af[mi], bfv[ni], acc[mi][ni], 0, 0, 0);
        }
        __syncthreads();
        cur ^= 1;
    }

#pragma unroll
    for (int mi = 0; mi < 3; ++mi) {
        int mrow = wr * 48 + mi * 16 + (l >> 4) * 4;
#pragma unroll
        for (int ni = 0; ni < 2; ++ni) {
            int n = h0 + wc * 32 + ni * 16 + (l & 15);
            float bv = bias[n];
            ushort4 rt = *(const ushort4*)(xwT + (size_t)(Rq * 256 + n) * NPq + b * 96 + mrow);
#pragma unroll
            for (int j = 0; j < 4; ++j) {
                int m = mrow + j;
                float rv = bf2f(j == 0 ? rt.x : j == 1 ? rt.y : j == 2 ? rt.z : rt.w);
                if (m < NPGq)
                    out[((size_t)b * NPGq + m) * Hq + n] = acc[mi][ni][j] + rv + bv;
            }
        }
    }
}

extern "C" void kernel_launch(void* const* d_in, const int* in_sizes, int n_in,
                              void* d_out, int out_size, void* d_ws, size_t ws_size,
                              hipStream_t stream) {
    (void)in_sizes; (void)n_in; (void)out_size; (void)ws_size;
    const float* M     = (const float*)d_in[0];
    const float* x     = (const float*)d_in[1];
    const float* natt  = (const float*)d_in[2];
    const float* Ws    = (const float*)d_in[3];
    const float* bases = (const float*)d_in[4];
    const float* comp  = (const float*)d_in[5];
    const float* rootw = (const float*)d_in[6];
    const float* bias  = (const float*)d_in[7];
    const int* esrc    = (const int*)d_in[8];
    const int* edst    = (const int*)d_in[9];
    const int* etype   = (const int*)d_in[10];
    float* out = (float*)d_out;
    char* ws = (char*)d_ws;

    unsigned short* Wt  = (unsigned short*)(ws + 0);          //    786,432 B
    float* A2f   = (float*)(ws + 786432);                     // 11,796,480 B
    unsigned short* A2b = (unsigned short*)(ws + 12582912);   //  5,898,240 B
    unsigned short* xb  = (unsigned short*)(ws + 18481152);   //  3,145,728 B
    unsigned short* xwT = (unsigned short*)(ws + 21626880);   // 18,874,368 B (total ~40.5 MB)

    k_prep<<<dim3(3696), 256, 0, stream>>>(x, bases, comp, rootw, xb, Wt, A2f);
    k_attn<<<dim3(Bq), 256, 0, stream>>>(M, Ws, natt, esrc, edst, etype, A2f);
    k_a2bf<<<dim3((Bq * 96 * KAq / 8 + 255) / 256), 256, 0, stream>>>(A2f, A2b);
    k_gemm1<<<dim3(KKq / 64, NPq / 64), 256, 0, stream>>>(Wt, xb, xwT);
    k_gemm2<<<dim3(Bq, Hq / 64), 256, 0, stream>>>(A2b, xwT, bias, out);
}